// Round 12
// baseline (502.279 us; speedup 1.0000x reference)
//
#include <hip/hip_runtime.h>

constexpr int NN = 100000;
constexpr int NE = 1600000;
constexpr int NG = 64;
constexpr int H  = 128;

constexpr int NB  = 392;       // dst buckets (dst >> 8, 256 nodes each)
constexpr int CAP = 5120;      // ebuf capacity per bucket (mean 4082, sigma ~64)
constexpr int P1B = 256;       // pass-1 blocks
constexpr int EPB = NE / P1B;  // 6250 edges per pass-1 block

typedef float v2f   __attribute__((ext_vector_type(2)));
typedef float f32x4 __attribute__((ext_vector_type(4)));
typedef short short8 __attribute__((ext_vector_type(8)));

// ---------- bf16 helpers ----------
__device__ __forceinline__ float bf_lo(unsigned v) { return __uint_as_float(v << 16); }
__device__ __forceinline__ float bf_hi(unsigned v) { return __uint_as_float(v & 0xffff0000u); }
__device__ __forceinline__ unsigned bf_pack(float a, float b) {  // RTNE
  unsigned ua = __float_as_uint(a);
  unsigned ub = __float_as_uint(b);
  ua += 0x7fffu + ((ua >> 16) & 1u);
  ub += 0x7fffu + ((ub >> 16) & 1u);
  return (ua >> 16) | (ub & 0xffff0000u);
}
__device__ __forceinline__ ushort bf1(float a) {
  unsigned u = __float_as_uint(a);
  u += 0x7fffu + ((u >> 16) & 1u);
  return (ushort)(u >> 16);
}

// ---------- init: pool/cnt zero + bucket cursors ----------
__global__ void k_init(float* pool, float* cnt, int* gcursor) {
  int i = blockIdx.x * blockDim.x + threadIdx.x;
  if (i < NG * H) pool[i] = 0.f;
  if (i < NG) cnt[i] = 0.f;
  if (i < NB) gcursor[i] = i * CAP;
}

// ---------- pass 1: bucket edges by dst>>8 (LDS histogram + chunk reserve) ----------
__global__ void k_bucket(const int* __restrict__ ei, int* __restrict__ gcursor,
                         unsigned* __restrict__ ebuf, int* __restrict__ dirs,
                         ushort* __restrict__ dirl) {
  __shared__ int cnt[NB];
  __shared__ int cpos[NB];
  int t = threadIdx.x, b = blockIdx.x;
  for (int j = t; j < NB; j += 256) cnt[j] = 0;
  __syncthreads();
  int e0 = b * EPB;
  for (int i = t; i < EPB; i += 256) {
    int d = ei[NE + e0 + i];
    atomicAdd(&cnt[d >> 8], 1);
  }
  __syncthreads();
  for (int j = t; j < NB; j += 256) {
    int c = cnt[j];
    int start = atomicAdd(&gcursor[j], c);
    cpos[j] = start;
    dirs[b * NB + j] = start;
    dirl[b * NB + j] = (ushort)c;
  }
  __syncthreads();
  for (int j = t; j < NB; j += 256) cnt[j] = 0;
  __syncthreads();
  for (int i = t; i < EPB; i += 256) {
    int s = ei[e0 + i];
    int d = ei[NE + e0 + i];
    int bk = d >> 8;
    int slot = cpos[bk] + atomicAdd(&cnt[bk], 1);
    ebuf[slot] = (unsigned)s | ((unsigned)(d & 255) << 17);  // src:17b | local:8b
  }
}

// ---------- tiny scan of bucket totals ----------
__global__ void k_bucketscan(const int* __restrict__ gcursor, int* __restrict__ gbase,
                             int* __restrict__ offs) {
  if (threadIdx.x == 0) {
    int run = 0;
    for (int j = 0; j < NB; ++j) {
      int tot = gcursor[j] - j * CAP;
      gbase[j] = run; run += tot;
    }
    gbase[NB] = run;
    offs[NN] = run;   // == NE
  }
}

// ---------- pass 2: per-bucket histogram/scan -> offs, dis, xs16, csr ----------
__global__ void k_csr(const unsigned* __restrict__ ebuf, const int* __restrict__ dirs,
                      const ushort* __restrict__ dirl, const int* __restrict__ gbase,
                      const float* __restrict__ x,
                      int* __restrict__ offs, float* __restrict__ dis,
                      unsigned* __restrict__ xs16, int* __restrict__ csr, int n) {
  __shared__ int histc[256];
  __shared__ int loffs[256];
  __shared__ int wps[4];
  int t = threadIdx.x, j = blockIdx.x;
  histc[t] = 0;
  __syncthreads();
  int cstart = dirs[t * NB + j];
  int clen = dirl[t * NB + j];
  for (int k = 0; k < clen; ++k) {
    unsigned u = ebuf[cstart + k];
    atomicAdd(&histc[u >> 17], 1);
  }
  __syncthreads();
  int h = histc[t];
  int inc = h;
  int lane = t & 63;
#pragma unroll
  for (int off = 1; off < 64; off <<= 1) {
    int y = __shfl_up(inc, off, 64);
    if (lane >= off) inc += y;
  }
  if (lane == 63) wps[t >> 6] = inc;
  __syncthreads();
  int woff = 0;
  for (int i = 0; i < (t >> 6); ++i) woff += wps[i];
  int excl = gbase[j] + woff + inc - h;
  loffs[t] = excl;
  int node = j * 256 + t;
  if (node < n) {
    offs[node] = excl;
    float dd = rsqrtf((float)(h + 1));
    dis[node] = dd;
    const float* xr = x + (size_t)node * 10;
#pragma unroll
    for (int q = 0; q < 8; ++q) {
      float a = (2 * q < 10) ? xr[2 * q] * dd : 0.f;
      float bb = (2 * q + 1 < 10) ? xr[2 * q + 1] * dd : 0.f;
      xs16[node * 8 + q] = bf_pack(a, bb);
    }
  }
  __syncthreads();
  for (int k = 0; k < clen; ++k) {
    unsigned u = ebuf[cstart + k];
    int src = (int)(u & 0x1FFFFu);
    int slot = atomicAdd(&loffs[u >> 17], 1);
    csr[slot] = src;
  }
}

// ---------- layer 1: gather 16-wide + dense 10x128 ----------

__global__ void k_gather16(const int* __restrict__ offs, const int* __restrict__ csr,
                           const float* __restrict__ dis, const unsigned* __restrict__ xs16,
                           float2* __restrict__ agg, int n) {
  int wid = (blockIdx.x * blockDim.x + threadIdx.x) >> 6;
  int lane = threadIdx.x & 63;
  int g = lane >> 3, sl = lane & 7;
  int node = wid * 8 + g;
  if (node >= n) return;
  unsigned self = xs16[node * 8 + sl];
  float sx = bf_lo(self), sy = bf_hi(self);
  float tx = 0.f, ty = 0.f;
  int e = offs[node], end = offs[node + 1];
  for (; e + 3 < end; e += 4) {
    int s[4];
#pragma unroll
    for (int j = 0; j < 4; ++j) s[j] = csr[e + j];
    unsigned u[4];
#pragma unroll
    for (int j = 0; j < 4; ++j) u[j] = xs16[s[j] * 8 + sl];
    sx += bf_lo(u[0]) + bf_lo(u[1]); tx += bf_lo(u[2]) + bf_lo(u[3]);
    sy += bf_hi(u[0]) + bf_hi(u[1]); ty += bf_hi(u[2]) + bf_hi(u[3]);
  }
  for (; e < end; ++e) {
    unsigned v0 = xs16[csr[e] * 8 + sl];
    sx += bf_lo(v0); sy += bf_hi(v0);
  }
  float dd = dis[node];
  float2 o; o.x = (sx + tx) * dd; o.y = (sy + ty) * dd;
  agg[node * 8 + sl] = o;
}

__global__ void k_mm16(const float* __restrict__ agg, const float* __restrict__ W1,
                       const float* __restrict__ b1, ushort* __restrict__ xbuf, int n) {
  int node = blockIdx.x;
  if (node >= n) return;
  __shared__ float as[16];
  int m = threadIdx.x;
  if (m < 16) as[m] = agg[node * 16 + m];
  __syncthreads();
  float s = 0.f;
#pragma unroll
  for (int k = 0; k < 10; ++k) s += as[k] * W1[k * H + m];
  s += b1[m];
  xbuf[node * H + m] = bf1(fmaxf(s, 0.f));
}

// ---------- W2+W3 -> A-fragment pack (bf16), layout [nt][ks][lane][j] ----------
__global__ void k_cvtW2(const float* __restrict__ W2, const float* __restrict__ W3,
                        short* __restrict__ WfragA, short* __restrict__ WfragB) {
  int i = blockIdx.x * blockDim.x + threadIdx.x;  // 32768
  const float* W = (i < 16384) ? W2 : W3;
  short* outp = (i < 16384) ? WfragA : WfragB;
  int ii = i & 16383;
  int jj = ii & 7, lane = (ii >> 3) & 63, ks = (ii >> 9) & 3, nt = ii >> 11;
  int feat = nt * 16 + (lane & 15);
  int k = ks * 32 + (lane >> 4) * 8 + jj;
  outp[ii] = (short)bf1(W[k * H + feat]);
}

// ---------- layers 2/3 dense via MFMA: hs8 = fp8( (xb @ W) * dis ) ----------
__global__ void k_mm128_mfma(const short* __restrict__ xb,     // bf16 [n][128]
                             const short* __restrict__ Wfrag,  // [8][4][64][8]
                             const float* __restrict__ dis,
                             unsigned* __restrict__ hs8, int n) {
  int t = threadIdx.x;
  int lane = t & 63, w = t >> 6;
  int nbase = blockIdx.x * 64 + w * 16;
  int node = nbase + (lane & 15);
  bool valid = node < n;
  int nc = valid ? node : (n - 1);
  short8 xf[4];
  const short* xrow = xb + (size_t)nc * H + (lane >> 4) * 8;
#pragma unroll
  for (int ks = 0; ks < 4; ++ks)
    xf[ks] = *(const short8*)(xrow + ks * 32);
  float d = dis[nc];
  const short8* wf = (const short8*)Wfrag;
#pragma unroll
  for (int nt = 0; nt < 8; ++nt) {
    f32x4 acc = {0.f, 0.f, 0.f, 0.f};
#pragma unroll
    for (int ks = 0; ks < 4; ++ks) {
      short8 af = wf[(nt * 4 + ks) * 64 + lane];
      acc = __builtin_amdgcn_mfma_f32_16x16x32_bf16(af, xf[ks], acc, 0, 0, 0);
    }
    if (valid) {
      int pk = __builtin_amdgcn_cvt_pk_fp8_f32(acc[0] * d, acc[1] * d, 0, false);
      pk = __builtin_amdgcn_cvt_pk_fp8_f32(acc[2] * d, acc[3] * d, pk, true);
      hs8[node * 32 + nt * 4 + (lane >> 4)] = (unsigned)pk;
    }
  }
}

// ---------- gather 128-wide: one node per wave, TWO edges per VMEM inst ----------
// hs rows read as u32 (4 fp8 feats/lane): lanes 0-31 fetch row A, lanes 32-63
// row B of an edge pair. Halves merged at the end via shfl_xor(32).
template <bool RELU, bool BIAS, bool OUTBF>
__global__ void k_gather(const int* __restrict__ offs, const int* __restrict__ csr,
                         const float* __restrict__ dis, const unsigned* __restrict__ hsu,
                         const float* __restrict__ b, void* __restrict__ outp, int n) {
  int node = (blockIdx.x * blockDim.x + threadIdx.x) >> 6;
  node = __builtin_amdgcn_readfirstlane(node);
  int lane = threadIdx.x & 63;
  int q = lane & 31;
  bool hihalf = lane >= 32;
  if (node >= n) return;
  float a0 = 0.f, a1 = 0.f, a2 = 0.f, a3 = 0.f;
  float mhi = hihalf ? 0.f : 1.f;   // mask for half-1-absent slots
  int e = __builtin_amdgcn_readfirstlane(offs[node]);
  int end = __builtin_amdgcn_readfirstlane(offs[node + 1]);

  // prologue pair: self (half 0) + first edge (half 1, masked if absent)
  {
    bool haveB = e < end;
    int sB = haveB ? __builtin_amdgcn_readfirstlane(csr[e]) : node;
    int sel = hihalf ? sB : node;
    unsigned u = hsu[(size_t)sel * 32 + q];
    v2f lo = __builtin_amdgcn_cvt_pk_f32_fp8((int)u, false);
    v2f hi = __builtin_amdgcn_cvt_pk_f32_fp8((int)u, true);
    if (haveB) {
      a0 += lo.x; a1 += lo.y; a2 += hi.x; a3 += hi.y;
      ++e;
    } else {
      a0 += lo.x * mhi; a1 += lo.y * mhi; a2 += hi.x * mhi; a3 += hi.y * mhi;
    }
  }

  for (; e + 15 < end; e += 16) {   // 8 pairs
    int s[16];
#pragma unroll
    for (int j = 0; j < 16; ++j) s[j] = __builtin_amdgcn_readfirstlane(csr[e + j]);
    unsigned u[8];
#pragma unroll
    for (int j = 0; j < 8; ++j) {
      int sel = hihalf ? s[2 * j + 1] : s[2 * j];
      u[j] = hsu[(size_t)sel * 32 + q];
    }
#pragma unroll
    for (int j = 0; j < 8; ++j) {
      v2f lo = __builtin_amdgcn_cvt_pk_f32_fp8((int)u[j], false);
      v2f hi = __builtin_amdgcn_cvt_pk_f32_fp8((int)u[j], true);
      a0 += lo.x; a1 += lo.y; a2 += hi.x; a3 += hi.y;
    }
  }
  if (e + 7 < end) {                // 4 pairs
    int s[8];
#pragma unroll
    for (int j = 0; j < 8; ++j) s[j] = __builtin_amdgcn_readfirstlane(csr[e + j]);
    unsigned u[4];
#pragma unroll
    for (int j = 0; j < 4; ++j) {
      int sel = hihalf ? s[2 * j + 1] : s[2 * j];
      u[j] = hsu[(size_t)sel * 32 + q];
    }
#pragma unroll
    for (int j = 0; j < 4; ++j) {
      v2f lo = __builtin_amdgcn_cvt_pk_f32_fp8((int)u[j], false);
      v2f hi = __builtin_amdgcn_cvt_pk_f32_fp8((int)u[j], true);
      a0 += lo.x; a1 += lo.y; a2 += hi.x; a3 += hi.y;
    }
    e += 8;
  }
  if (e + 3 < end) {                // 2 pairs
    int s0 = __builtin_amdgcn_readfirstlane(csr[e]);
    int s1 = __builtin_amdgcn_readfirstlane(csr[e + 1]);
    int s2 = __builtin_amdgcn_readfirstlane(csr[e + 2]);
    int s3 = __builtin_amdgcn_readfirstlane(csr[e + 3]);
    int selA = hihalf ? s1 : s0;
    int selB = hihalf ? s3 : s2;
    unsigned uA = hsu[(size_t)selA * 32 + q];
    unsigned uB = hsu[(size_t)selB * 32 + q];
    v2f lo = __builtin_amdgcn_cvt_pk_f32_fp8((int)uA, false);
    v2f hi = __builtin_amdgcn_cvt_pk_f32_fp8((int)uA, true);
    a0 += lo.x; a1 += lo.y; a2 += hi.x; a3 += hi.y;
    lo = __builtin_amdgcn_cvt_pk_f32_fp8((int)uB, false);
    hi = __builtin_amdgcn_cvt_pk_f32_fp8((int)uB, true);
    a0 += lo.x; a1 += lo.y; a2 += hi.x; a3 += hi.y;
    e += 4;
  }
  if (e + 1 < end) {                // 1 pair
    int s0 = __builtin_amdgcn_readfirstlane(csr[e]);
    int s1 = __builtin_amdgcn_readfirstlane(csr[e + 1]);
    int sel = hihalf ? s1 : s0;
    unsigned u = hsu[(size_t)sel * 32 + q];
    v2f lo = __builtin_amdgcn_cvt_pk_f32_fp8((int)u, false);
    v2f hi = __builtin_amdgcn_cvt_pk_f32_fp8((int)u, true);
    a0 += lo.x; a1 += lo.y; a2 += hi.x; a3 += hi.y;
    e += 2;
  }
  if (e < end) {                    // final single edge (half 0 only, uniform row)
    int s0 = __builtin_amdgcn_readfirstlane(csr[e]);
    unsigned u = hsu[(size_t)s0 * 32 + q];
    v2f lo = __builtin_amdgcn_cvt_pk_f32_fp8((int)u, false);
    v2f hi = __builtin_amdgcn_cvt_pk_f32_fp8((int)u, true);
    a0 += lo.x * mhi; a1 += lo.y * mhi; a2 += hi.x * mhi; a3 += hi.y * mhi;
  }

  // merge halves
  a0 += __shfl_xor(a0, 32, 64);
  a1 += __shfl_xor(a1, 32, 64);
  a2 += __shfl_xor(a2, 32, 64);
  a3 += __shfl_xor(a3, 32, 64);

  if (!hihalf) {
    float dd = dis[node];
    float v0 = a0 * dd, v1 = a1 * dd, v2 = a2 * dd, v3 = a3 * dd;
    if (BIAS) {
      float4 bb = ((const float4*)b)[q];
      v0 += bb.x; v1 += bb.y; v2 += bb.z; v3 += bb.w;
    }
    if (RELU) {
      v0 = fmaxf(v0, 0.f); v1 = fmaxf(v1, 0.f);
      v2 = fmaxf(v2, 0.f); v3 = fmaxf(v3, 0.f);
    }
    if (OUTBF) {
      uint2 o;
      o.x = bf_pack(v0, v1);
      o.y = bf_pack(v2, v3);
      ((uint2*)outp)[(size_t)node * 32 + q] = o;
    } else {
      float4 o; o.x = v0; o.y = v1; o.z = v2; o.w = v3;
      ((float4*)outp)[(size_t)node * 32 + q] = o;
    }
  }
}

// ---------- pooling / output ----------

// acc is bf16 [n][128]
__global__ void k_pool(const ushort* __restrict__ acc, const float* __restrict__ b3,
                       const int* __restrict__ batch, float* pool, float* cnt, int n) {
  int m = threadIdx.x;
  int n0 = blockIdx.x * 64;
  float run = 0.f, crun = 0.f;
  int curg = -1;
  float bm = b3[m];
  for (int i = 0; i < 64; ++i) {
    int node = n0 + i;
    if (node >= n) break;
    int g = batch[node];
    if (g != curg) {
      if (curg >= 0) {
        atomicAdd(&pool[curg * H + m], run);
        if (m == 0) atomicAdd(&cnt[curg], crun);
      }
      curg = g; run = 0.f; crun = 0.f;
    }
    run += __uint_as_float((unsigned)acc[node * H + m] << 16) + bm;
    crun += 1.f;
  }
  if (curg >= 0) {
    atomicAdd(&pool[curg * H + m], run);
    if (m == 0) atomicAdd(&cnt[curg], crun);
  }
}

__global__ void k_out(const float* __restrict__ pool, const float* __restrict__ cnt,
                      const float* __restrict__ Wlin, const float* __restrict__ blin,
                      float* __restrict__ out) {
  int t = threadIdx.x;
  if (t >= NG * 3) return;
  int g = t / 3, c = t % 3;
  float invc = 1.f / fmaxf(cnt[g], 1.f);
  float s = 0.f;
  for (int m = 0; m < H; ++m) s += pool[g * H + m] * Wlin[m * 3 + c];
  out[t] = s * invc + blin[c];
}

extern "C" void kernel_launch(void* const* d_in, const int* in_sizes, int n_in,
                              void* d_out, int out_size, void* d_ws, size_t ws_size,
                              hipStream_t stream) {
  const float* x     = (const float*)d_in[0];
  const int*   ei    = (const int*)d_in[1];
  const int*   batch = (const int*)d_in[2];
  const float* W1    = (const float*)d_in[3];
  const float* b1    = (const float*)d_in[4];
  const float* W2    = (const float*)d_in[5];
  const float* b2    = (const float*)d_in[6];
  const float* W3    = (const float*)d_in[7];
  const float* b3    = (const float*)d_in[8];
  const float* Wlin  = (const float*)d_in[9];
  const float* blin  = (const float*)d_in[10];
  float* out = (float*)d_out;

  char* ws = (char*)d_ws;
  float*    dis    = (float*)ws;     ws += sizeof(float) * NN;
  unsigned* hs8    = (unsigned*)ws;  ws += (size_t)NN * H;                  // fp8
  ushort*   xbuf   = (ushort*)ws;    ws += sizeof(ushort) * (size_t)NN * H; // bf16
  short*    WfragA = (short*)ws;     ws += sizeof(short) * 16384;
  short*    WfragB = (short*)ws;     ws += sizeof(short) * 16384;
  unsigned* xs16   = (unsigned*)ws;  ws += sizeof(unsigned) * (size_t)NN * 8;
  float*    agg    = (float*)ws;     ws += sizeof(float) * (size_t)NN * 16;
  float*    pool   = (float*)ws;     ws += sizeof(float) * NG * H;
  float*    cnt    = (float*)ws;     ws += sizeof(float) * NG;
  int*      offs   = (int*)ws;       ws += sizeof(int) * (NN + 8);
  int*      csr    = (int*)ws;       ws += sizeof(int) * NE;
  unsigned* ebuf   = (unsigned*)ws;  ws += sizeof(unsigned) * (size_t)NB * CAP;
  int*      dirs   = (int*)ws;       ws += sizeof(int) * P1B * NB;
  ushort*   dirl   = (ushort*)ws;    ws += sizeof(ushort) * P1B * NB;
  int*      gcur   = (int*)ws;       ws += sizeof(int) * NB;
  int*      gbase  = (int*)ws;       ws += sizeof(int) * (NB + 1);

  // CSR build: LDS-bucketed counting sort (no fine-grained device atomics)
  k_init<<<32, 256, 0, stream>>>(pool, cnt, gcur);
  k_bucket<<<P1B, 256, 0, stream>>>(ei, gcur, ebuf, dirs, dirl);
  k_bucketscan<<<1, 64, 0, stream>>>(gcur, gbase, offs);
  k_csr<<<NB, 256, 0, stream>>>(ebuf, dirs, dirl, gbase, x, offs, dis, xs16, csr, NN);
  k_cvtW2<<<128, 256, 0, stream>>>(W2, W3, WfragA, WfragB);

  const int GATHER_GRID = (NN + 3) / 4;   // 1 node/wave, 4 waves/block
  const int MM_GRID = (NN + 63) / 64;     // 64 nodes/block (16/wave)

  // layer 1: aggregate-first (A·X)·W1
  k_gather16<<<(NN + 31) / 32, 256, 0, stream>>>(offs, csr, dis, xs16, (float2*)agg, NN);
  k_mm16<<<NN, 128, 0, stream>>>(agg, W1, b1, xbuf, NN);

  // layer 2
  k_mm128_mfma<<<MM_GRID, 256, 0, stream>>>((const short*)xbuf, WfragA, dis, hs8, NN);
  k_gather<true, true, true><<<GATHER_GRID, 256, 0, stream>>>(
      offs, csr, dis, hs8, b2, xbuf, NN);

  // layer 3
  k_mm128_mfma<<<MM_GRID, 256, 0, stream>>>((const short*)xbuf, WfragB, dis, hs8, NN);
  k_gather<false, false, true><<<GATHER_GRID, 256, 0, stream>>>(
      offs, csr, dis, hs8, nullptr, xbuf, NN);

  // pool + head
  k_pool<<<(NN + 63) / 64, 128, 0, stream>>>(xbuf, b3, batch, pool, cnt, NN);
  k_out<<<1, 256, 0, stream>>>(pool, cnt, Wlin, blin, out);
}

// Round 13
// 501.039 us; speedup vs baseline: 1.0025x; 1.0025x over previous
//
#include <hip/hip_runtime.h>

constexpr int NN = 100000;
constexpr int NE = 1600000;
constexpr int NG = 64;
constexpr int H  = 128;

constexpr int NB  = 392;       // dst buckets (dst >> 8, 256 nodes each)
constexpr int CAP = 5120;      // ebuf capacity per bucket (mean 4082, sigma ~64)
constexpr int P1B = 256;       // pass-1 blocks
constexpr int EPB = NE / P1B;  // 6250 edges per pass-1 block

typedef float v2f   __attribute__((ext_vector_type(2)));
typedef float f32x4 __attribute__((ext_vector_type(4)));
typedef short short8 __attribute__((ext_vector_type(8)));

// ---------- bf16 helpers ----------
__device__ __forceinline__ float bf_lo(unsigned v) { return __uint_as_float(v << 16); }
__device__ __forceinline__ float bf_hi(unsigned v) { return __uint_as_float(v & 0xffff0000u); }
__device__ __forceinline__ unsigned bf_pack(float a, float b) {  // RTNE
  unsigned ua = __float_as_uint(a);
  unsigned ub = __float_as_uint(b);
  ua += 0x7fffu + ((ua >> 16) & 1u);
  ub += 0x7fffu + ((ub >> 16) & 1u);
  return (ua >> 16) | (ub & 0xffff0000u);
}
__device__ __forceinline__ ushort bf1(float a) {
  unsigned u = __float_as_uint(a);
  u += 0x7fffu + ((u >> 16) & 1u);
  return (ushort)(u >> 16);
}

// lane ^ 32 exchange via ds_bpermute (no LDS block, no bank conflicts)
__device__ __forceinline__ float swap32(float v) {
  int idx = (((int)threadIdx.x & 63) ^ 32) << 2;
  return __int_as_float(__builtin_amdgcn_ds_bpermute(idx, __float_as_int(v)));
}

// ---------- init: pool/cnt zero + bucket cursors ----------
__global__ void k_init(float* pool, float* cnt, int* gcursor) {
  int i = blockIdx.x * blockDim.x + threadIdx.x;
  if (i < NG * H) pool[i] = 0.f;
  if (i < NG) cnt[i] = 0.f;
  if (i < NB) gcursor[i] = i * CAP;
}

// ---------- pass 1: bucket edges by dst>>8 (LDS histogram + chunk reserve) ----------
__global__ void k_bucket(const int* __restrict__ ei, int* __restrict__ gcursor,
                         unsigned* __restrict__ ebuf, int* __restrict__ dirs,
                         ushort* __restrict__ dirl) {
  __shared__ int cnt[NB];
  __shared__ int cpos[NB];
  int t = threadIdx.x, b = blockIdx.x;
  for (int j = t; j < NB; j += 256) cnt[j] = 0;
  __syncthreads();
  int e0 = b * EPB;
  for (int i = t; i < EPB; i += 256) {
    int d = ei[NE + e0 + i];
    atomicAdd(&cnt[d >> 8], 1);
  }
  __syncthreads();
  for (int j = t; j < NB; j += 256) {
    int c = cnt[j];
    int start = atomicAdd(&gcursor[j], c);
    cpos[j] = start;
    dirs[b * NB + j] = start;
    dirl[b * NB + j] = (ushort)c;
  }
  __syncthreads();
  for (int j = t; j < NB; j += 256) cnt[j] = 0;
  __syncthreads();
  for (int i = t; i < EPB; i += 256) {
    int s = ei[e0 + i];
    int d = ei[NE + e0 + i];
    int bk = d >> 8;
    int slot = cpos[bk] + atomicAdd(&cnt[bk], 1);
    ebuf[slot] = (unsigned)s | ((unsigned)(d & 255) << 17);  // src:17b | local:8b
  }
}

// ---------- tiny scan of bucket totals ----------
__global__ void k_bucketscan(const int* __restrict__ gcursor, int* __restrict__ gbase,
                             int* __restrict__ offs) {
  if (threadIdx.x == 0) {
    int run = 0;
    for (int j = 0; j < NB; ++j) {
      int tot = gcursor[j] - j * CAP;
      gbase[j] = run; run += tot;
    }
    gbase[NB] = run;
    offs[NN] = run;   // == NE
  }
}

// ---------- pass 2: per-bucket histogram/scan -> offs, dis, xs16, csr ----------
__global__ void k_csr(const unsigned* __restrict__ ebuf, const int* __restrict__ dirs,
                      const ushort* __restrict__ dirl, const int* __restrict__ gbase,
                      const float* __restrict__ x,
                      int* __restrict__ offs, float* __restrict__ dis,
                      unsigned* __restrict__ xs16, int* __restrict__ csr, int n) {
  __shared__ int histc[256];
  __shared__ int loffs[256];
  __shared__ int wps[4];
  int t = threadIdx.x, j = blockIdx.x;
  histc[t] = 0;
  __syncthreads();
  int cstart = dirs[t * NB + j];
  int clen = dirl[t * NB + j];
  for (int k = 0; k < clen; ++k) {
    unsigned u = ebuf[cstart + k];
    atomicAdd(&histc[u >> 17], 1);
  }
  __syncthreads();
  int h = histc[t];
  int inc = h;
  int lane = t & 63;
#pragma unroll
  for (int off = 1; off < 64; off <<= 1) {
    int y = __shfl_up(inc, off, 64);
    if (lane >= off) inc += y;
  }
  if (lane == 63) wps[t >> 6] = inc;
  __syncthreads();
  int woff = 0;
  for (int i = 0; i < (t >> 6); ++i) woff += wps[i];
  int excl = gbase[j] + woff + inc - h;
  loffs[t] = excl;
  int node = j * 256 + t;
  if (node < n) {
    offs[node] = excl;
    float dd = rsqrtf((float)(h + 1));
    dis[node] = dd;
    const float* xr = x + (size_t)node * 10;
#pragma unroll
    for (int q = 0; q < 8; ++q) {
      float a = (2 * q < 10) ? xr[2 * q] * dd : 0.f;
      float bb = (2 * q + 1 < 10) ? xr[2 * q + 1] * dd : 0.f;
      xs16[node * 8 + q] = bf_pack(a, bb);
    }
  }
  __syncthreads();
  for (int k = 0; k < clen; ++k) {
    unsigned u = ebuf[cstart + k];
    int src = (int)(u & 0x1FFFFu);
    int slot = atomicAdd(&loffs[u >> 17], 1);
    csr[slot] = src;
  }
}

// ---------- layer 1: gather 16-wide + dense 10x128 ----------

__global__ void k_gather16(const int* __restrict__ offs, const int* __restrict__ csr,
                           const float* __restrict__ dis, const unsigned* __restrict__ xs16,
                           float2* __restrict__ agg, int n) {
  int wid = (blockIdx.x * blockDim.x + threadIdx.x) >> 6;
  int lane = threadIdx.x & 63;
  int g = lane >> 3, sl = lane & 7;
  int node = wid * 8 + g;
  if (node >= n) return;
  unsigned self = xs16[node * 8 + sl];
  float sx = bf_lo(self), sy = bf_hi(self);
  float tx = 0.f, ty = 0.f;
  int e = offs[node], end = offs[node + 1];
  for (; e + 3 < end; e += 4) {
    int s[4];
#pragma unroll
    for (int j = 0; j < 4; ++j) s[j] = csr[e + j];
    unsigned u[4];
#pragma unroll
    for (int j = 0; j < 4; ++j) u[j] = xs16[s[j] * 8 + sl];
    sx += bf_lo(u[0]) + bf_lo(u[1]); tx += bf_lo(u[2]) + bf_lo(u[3]);
    sy += bf_hi(u[0]) + bf_hi(u[1]); ty += bf_hi(u[2]) + bf_hi(u[3]);
  }
  for (; e < end; ++e) {
    unsigned v0 = xs16[csr[e] * 8 + sl];
    sx += bf_lo(v0); sy += bf_hi(v0);
  }
  float dd = dis[node];
  float2 o; o.x = (sx + tx) * dd; o.y = (sy + ty) * dd;
  agg[node * 8 + sl] = o;
}

__global__ void k_mm16(const float* __restrict__ agg, const float* __restrict__ W1,
                       const float* __restrict__ b1, ushort* __restrict__ xbuf, int n) {
  int node = blockIdx.x;
  if (node >= n) return;
  __shared__ float as[16];
  int m = threadIdx.x;
  if (m < 16) as[m] = agg[node * 16 + m];
  __syncthreads();
  float s = 0.f;
#pragma unroll
  for (int k = 0; k < 10; ++k) s += as[k] * W1[k * H + m];
  s += b1[m];
  xbuf[node * H + m] = bf1(fmaxf(s, 0.f));
}

// ---------- W2+W3 -> A-fragment pack (bf16), layout [nt][ks][lane][j] ----------
__global__ void k_cvtW2(const float* __restrict__ W2, const float* __restrict__ W3,
                        short* __restrict__ WfragA, short* __restrict__ WfragB) {
  int i = blockIdx.x * blockDim.x + threadIdx.x;  // 32768
  const float* W = (i < 16384) ? W2 : W3;
  short* outp = (i < 16384) ? WfragA : WfragB;
  int ii = i & 16383;
  int jj = ii & 7, lane = (ii >> 3) & 63, ks = (ii >> 9) & 3, nt = ii >> 11;
  int feat = nt * 16 + (lane & 15);
  int k = ks * 32 + (lane >> 4) * 8 + jj;
  outp[ii] = (short)bf1(W[k * H + feat]);
}

// ---------- layers 2/3 dense via MFMA: hs8 = fp8( (xb @ W) * dis ) ----------
__global__ void k_mm128_mfma(const short* __restrict__ xb,     // bf16 [n][128]
                             const short* __restrict__ Wfrag,  // [8][4][64][8]
                             const float* __restrict__ dis,
                             unsigned* __restrict__ hs8, int n) {
  int t = threadIdx.x;
  int lane = t & 63, w = t >> 6;
  int nbase = blockIdx.x * 64 + w * 16;
  int node = nbase + (lane & 15);
  bool valid = node < n;
  int nc = valid ? node : (n - 1);
  short8 xf[4];
  const short* xrow = xb + (size_t)nc * H + (lane >> 4) * 8;
#pragma unroll
  for (int ks = 0; ks < 4; ++ks)
    xf[ks] = *(const short8*)(xrow + ks * 32);
  float d = dis[nc];
  const short8* wf = (const short8*)Wfrag;
#pragma unroll
  for (int nt = 0; nt < 8; ++nt) {
    f32x4 acc = {0.f, 0.f, 0.f, 0.f};
#pragma unroll
    for (int ks = 0; ks < 4; ++ks) {
      short8 af = wf[(nt * 4 + ks) * 64 + lane];
      acc = __builtin_amdgcn_mfma_f32_16x16x32_bf16(af, xf[ks], acc, 0, 0, 0);
    }
    if (valid) {
      int pk = __builtin_amdgcn_cvt_pk_fp8_f32(acc[0] * d, acc[1] * d, 0, false);
      pk = __builtin_amdgcn_cvt_pk_fp8_f32(acc[2] * d, acc[3] * d, pk, true);
      hs8[node * 32 + nt * 4 + (lane >> 4)] = (unsigned)pk;
    }
  }
}

// ---------- gather 128-wide: one node per wave, TWO edges per VMEM inst ----------
// hs rows read as u32 (4 fp8 feats/lane): lanes 0-31 fetch row A, lanes 32-63
// row B of an edge pair. Halves merged at the end via ds_bpermute (lane^32).
template <bool RELU, bool BIAS, bool OUTBF>
__global__ void k_gather(const int* __restrict__ offs, const int* __restrict__ csr,
                         const float* __restrict__ dis, const unsigned* __restrict__ hsu,
                         const float* __restrict__ b, void* __restrict__ outp, int n) {
  int node = (blockIdx.x * blockDim.x + threadIdx.x) >> 6;
  node = __builtin_amdgcn_readfirstlane(node);
  int lane = threadIdx.x & 63;
  int q = lane & 31;
  bool hihalf = lane >= 32;
  if (node >= n) return;
  float a0 = 0.f, a1 = 0.f, a2 = 0.f, a3 = 0.f;
  float mhi = hihalf ? 0.f : 1.f;   // mask for half-1-absent slots
  int e = __builtin_amdgcn_readfirstlane(offs[node]);
  int end = __builtin_amdgcn_readfirstlane(offs[node + 1]);

  // prologue pair: self (half 0) + first edge (half 1, masked if absent)
  {
    bool haveB = e < end;
    int sB = haveB ? __builtin_amdgcn_readfirstlane(csr[e]) : node;
    int sel = hihalf ? sB : node;
    unsigned u = hsu[(size_t)sel * 32 + q];
    v2f lo = __builtin_amdgcn_cvt_pk_f32_fp8((int)u, false);
    v2f hi = __builtin_amdgcn_cvt_pk_f32_fp8((int)u, true);
    if (haveB) {
      a0 += lo.x; a1 += lo.y; a2 += hi.x; a3 += hi.y;
      ++e;
    } else {
      a0 += lo.x * mhi; a1 += lo.y * mhi; a2 += hi.x * mhi; a3 += hi.y * mhi;
    }
  }

  for (; e + 15 < end; e += 16) {   // 8 pairs
    int s[16];
#pragma unroll
    for (int j = 0; j < 16; ++j) s[j] = __builtin_amdgcn_readfirstlane(csr[e + j]);
    unsigned u[8];
#pragma unroll
    for (int j = 0; j < 8; ++j) {
      int sel = hihalf ? s[2 * j + 1] : s[2 * j];
      u[j] = hsu[(size_t)sel * 32 + q];
    }
#pragma unroll
    for (int j = 0; j < 8; ++j) {
      v2f lo = __builtin_amdgcn_cvt_pk_f32_fp8((int)u[j], false);
      v2f hi = __builtin_amdgcn_cvt_pk_f32_fp8((int)u[j], true);
      a0 += lo.x; a1 += lo.y; a2 += hi.x; a3 += hi.y;
    }
  }
  if (e + 7 < end) {                // 4 pairs
    int s[8];
#pragma unroll
    for (int j = 0; j < 8; ++j) s[j] = __builtin_amdgcn_readfirstlane(csr[e + j]);
    unsigned u[4];
#pragma unroll
    for (int j = 0; j < 4; ++j) {
      int sel = hihalf ? s[2 * j + 1] : s[2 * j];
      u[j] = hsu[(size_t)sel * 32 + q];
    }
#pragma unroll
    for (int j = 0; j < 4; ++j) {
      v2f lo = __builtin_amdgcn_cvt_pk_f32_fp8((int)u[j], false);
      v2f hi = __builtin_amdgcn_cvt_pk_f32_fp8((int)u[j], true);
      a0 += lo.x; a1 += lo.y; a2 += hi.x; a3 += hi.y;
    }
    e += 8;
  }
  if (e + 3 < end) {                // 2 pairs
    int s0 = __builtin_amdgcn_readfirstlane(csr[e]);
    int s1 = __builtin_amdgcn_readfirstlane(csr[e + 1]);
    int s2 = __builtin_amdgcn_readfirstlane(csr[e + 2]);
    int s3 = __builtin_amdgcn_readfirstlane(csr[e + 3]);
    int selA = hihalf ? s1 : s0;
    int selB = hihalf ? s3 : s2;
    unsigned uA = hsu[(size_t)selA * 32 + q];
    unsigned uB = hsu[(size_t)selB * 32 + q];
    v2f lo = __builtin_amdgcn_cvt_pk_f32_fp8((int)uA, false);
    v2f hi = __builtin_amdgcn_cvt_pk_f32_fp8((int)uA, true);
    a0 += lo.x; a1 += lo.y; a2 += hi.x; a3 += hi.y;
    lo = __builtin_amdgcn_cvt_pk_f32_fp8((int)uB, false);
    hi = __builtin_amdgcn_cvt_pk_f32_fp8((int)uB, true);
    a0 += lo.x; a1 += lo.y; a2 += hi.x; a3 += hi.y;
    e += 4;
  }
  if (e + 1 < end) {                // 1 pair
    int s0 = __builtin_amdgcn_readfirstlane(csr[e]);
    int s1 = __builtin_amdgcn_readfirstlane(csr[e + 1]);
    int sel = hihalf ? s1 : s0;
    unsigned u = hsu[(size_t)sel * 32 + q];
    v2f lo = __builtin_amdgcn_cvt_pk_f32_fp8((int)u, false);
    v2f hi = __builtin_amdgcn_cvt_pk_f32_fp8((int)u, true);
    a0 += lo.x; a1 += lo.y; a2 += hi.x; a3 += hi.y;
    e += 2;
  }
  if (e < end) {                    // final single edge (half 0 only, uniform row)
    int s0 = __builtin_amdgcn_readfirstlane(csr[e]);
    unsigned u = hsu[(size_t)s0 * 32 + q];
    v2f lo = __builtin_amdgcn_cvt_pk_f32_fp8((int)u, false);
    v2f hi = __builtin_amdgcn_cvt_pk_f32_fp8((int)u, true);
    a0 += lo.x * mhi; a1 += lo.y * mhi; a2 += hi.x * mhi; a3 += hi.y * mhi;
  }

  // merge halves via ds_bpermute lane^32 (no LDS block, no bank conflicts)
  a0 += swap32(a0);
  a1 += swap32(a1);
  a2 += swap32(a2);
  a3 += swap32(a3);

  if (!hihalf) {
    float dd = dis[node];
    float v0 = a0 * dd, v1 = a1 * dd, v2 = a2 * dd, v3 = a3 * dd;
    if (BIAS) {
      float4 bb = ((const float4*)b)[q];
      v0 += bb.x; v1 += bb.y; v2 += bb.z; v3 += bb.w;
    }
    if (RELU) {
      v0 = fmaxf(v0, 0.f); v1 = fmaxf(v1, 0.f);
      v2 = fmaxf(v2, 0.f); v3 = fmaxf(v3, 0.f);
    }
    if (OUTBF) {
      uint2 o;
      o.x = bf_pack(v0, v1);
      o.y = bf_pack(v2, v3);
      ((uint2*)outp)[(size_t)node * 32 + q] = o;
    } else {
      float4 o; o.x = v0; o.y = v1; o.z = v2; o.w = v3;
      ((float4*)outp)[(size_t)node * 32 + q] = o;
    }
  }
}

// ---------- pooling / output ----------

// acc is bf16 [n][128]
__global__ void k_pool(const ushort* __restrict__ acc, const float* __restrict__ b3,
                       const int* __restrict__ batch, float* pool, float* cnt, int n) {
  int m = threadIdx.x;
  int n0 = blockIdx.x * 64;
  float run = 0.f, crun = 0.f;
  int curg = -1;
  float bm = b3[m];
  for (int i = 0; i < 64; ++i) {
    int node = n0 + i;
    if (node >= n) break;
    int g = batch[node];
    if (g != curg) {
      if (curg >= 0) {
        atomicAdd(&pool[curg * H + m], run);
        if (m == 0) atomicAdd(&cnt[curg], crun);
      }
      curg = g; run = 0.f; crun = 0.f;
    }
    run += __uint_as_float((unsigned)acc[node * H + m] << 16) + bm;
    crun += 1.f;
  }
  if (curg >= 0) {
    atomicAdd(&pool[curg * H + m], run);
    if (m == 0) atomicAdd(&cnt[curg], crun);
  }
}

__global__ void k_out(const float* __restrict__ pool, const float* __restrict__ cnt,
                      const float* __restrict__ Wlin, const float* __restrict__ blin,
                      float* __restrict__ out) {
  int t = threadIdx.x;
  if (t >= NG * 3) return;
  int g = t / 3, c = t % 3;
  float invc = 1.f / fmaxf(cnt[g], 1.f);
  float s = 0.f;
  for (int m = 0; m < H; ++m) s += pool[g * H + m] * Wlin[m * 3 + c];
  out[t] = s * invc + blin[c];
}

extern "C" void kernel_launch(void* const* d_in, const int* in_sizes, int n_in,
                              void* d_out, int out_size, void* d_ws, size_t ws_size,
                              hipStream_t stream) {
  const float* x     = (const float*)d_in[0];
  const int*   ei    = (const int*)d_in[1];
  const int*   batch = (const int*)d_in[2];
  const float* W1    = (const float*)d_in[3];
  const float* b1    = (const float*)d_in[4];
  const float* W2    = (const float*)d_in[5];
  const float* b2    = (const float*)d_in[6];
  const float* W3    = (const float*)d_in[7];
  const float* b3    = (const float*)d_in[8];
  const float* Wlin  = (const float*)d_in[9];
  const float* blin  = (const float*)d_in[10];
  float* out = (float*)d_out;

  char* ws = (char*)d_ws;
  float*    dis    = (float*)ws;     ws += sizeof(float) * NN;
  unsigned* hs8    = (unsigned*)ws;  ws += (size_t)NN * H;                  // fp8
  ushort*   xbuf   = (ushort*)ws;    ws += sizeof(ushort) * (size_t)NN * H; // bf16
  short*    WfragA = (short*)ws;     ws += sizeof(short) * 16384;
  short*    WfragB = (short*)ws;     ws += sizeof(short) * 16384;
  unsigned* xs16   = (unsigned*)ws;  ws += sizeof(unsigned) * (size_t)NN * 8;
  float*    agg    = (float*)ws;     ws += sizeof(float) * (size_t)NN * 16;
  float*    pool   = (float*)ws;     ws += sizeof(float) * NG * H;
  float*    cnt    = (float*)ws;     ws += sizeof(float) * NG;
  int*      offs   = (int*)ws;       ws += sizeof(int) * (NN + 8);
  int*      csr    = (int*)ws;       ws += sizeof(int) * NE;
  unsigned* ebuf   = (unsigned*)ws;  ws += sizeof(unsigned) * (size_t)NB * CAP;
  int*      dirs   = (int*)ws;       ws += sizeof(int) * P1B * NB;
  ushort*   dirl   = (ushort*)ws;    ws += sizeof(ushort) * P1B * NB;
  int*      gcur   = (int*)ws;       ws += sizeof(int) * NB;
  int*      gbase  = (int*)ws;       ws += sizeof(int) * (NB + 1);

  // CSR build: LDS-bucketed counting sort (no fine-grained device atomics)
  k_init<<<32, 256, 0, stream>>>(pool, cnt, gcur);
  k_bucket<<<P1B, 256, 0, stream>>>(ei, gcur, ebuf, dirs, dirl);
  k_bucketscan<<<1, 64, 0, stream>>>(gcur, gbase, offs);
  k_csr<<<NB, 256, 0, stream>>>(ebuf, dirs, dirl, gbase, x, offs, dis, xs16, csr, NN);
  k_cvtW2<<<128, 256, 0, stream>>>(W2, W3, WfragA, WfragB);

  const int GATHER_GRID = (NN + 3) / 4;   // 1 node/wave, 4 waves/block
  const int MM_GRID = (NN + 63) / 64;     // 64 nodes/block (16/wave)

  // layer 1: aggregate-first (A·X)·W1
  k_gather16<<<(NN + 31) / 32, 256, 0, stream>>>(offs, csr, dis, xs16, (float2*)agg, NN);
  k_mm16<<<NN, 128, 0, stream>>>(agg, W1, b1, xbuf, NN);

  // layer 2
  k_mm128_mfma<<<MM_GRID, 256, 0, stream>>>((const short*)xbuf, WfragA, dis, hs8, NN);
  k_gather<true, true, true><<<GATHER_GRID, 256, 0, stream>>>(
      offs, csr, dis, hs8, b2, xbuf, NN);

  // layer 3
  k_mm128_mfma<<<MM_GRID, 256, 0, stream>>>((const short*)xbuf, WfragB, dis, hs8, NN);
  k_gather<false, false, true><<<GATHER_GRID, 256, 0, stream>>>(
      offs, csr, dis, hs8, nullptr, xbuf, NN);

  // pool + head
  k_pool<<<(NN + 63) / 64, 128, 0, stream>>>(xbuf, b3, batch, pool, cnt, NN);
  k_out<<<1, 256, 0, stream>>>(pool, cnt, Wlin, blin, out);
}

// Round 14
// 263.370 us; speedup vs baseline: 1.9071x; 1.9024x over previous
//
#include <hip/hip_runtime.h>

constexpr int NN = 100000;
constexpr int NE = 1600000;
constexpr int NG = 64;
constexpr int H  = 128;

constexpr int NB  = 392;       // dst buckets (dst >> 8, 256 nodes each)
constexpr int CAP = 5120;      // ebuf capacity per bucket (mean 4082, sigma ~64)
constexpr int P1B = 256;       // pass-1 blocks
constexpr int EPB = NE / P1B;  // 6250 edges per pass-1 block

typedef float v2f   __attribute__((ext_vector_type(2)));
typedef float f32x4 __attribute__((ext_vector_type(4)));
typedef short short8 __attribute__((ext_vector_type(8)));

// ---------- bf16 helpers ----------
__device__ __forceinline__ float bf_lo(unsigned v) { return __uint_as_float(v << 16); }
__device__ __forceinline__ float bf_hi(unsigned v) { return __uint_as_float(v & 0xffff0000u); }
__device__ __forceinline__ unsigned bf_pack(float a, float b) {  // RTNE
  unsigned ua = __float_as_uint(a);
  unsigned ub = __float_as_uint(b);
  ua += 0x7fffu + ((ua >> 16) & 1u);
  ub += 0x7fffu + ((ub >> 16) & 1u);
  return (ua >> 16) | (ub & 0xffff0000u);
}
__device__ __forceinline__ ushort bf1(float a) {
  unsigned u = __float_as_uint(a);
  u += 0x7fffu + ((u >> 16) & 1u);
  return (ushort)(u >> 16);
}

// lane ^ 32 exchange via ds_bpermute (no LDS allocation)
__device__ __forceinline__ float swap32(float v) {
  int idx = (((int)threadIdx.x & 63) ^ 32) << 2;
  return __int_as_float(__builtin_amdgcn_ds_bpermute(idx, __float_as_int(v)));
}

// ---------- init: pool/cnt zero + bucket cursors ----------
__global__ void k_init(float* pool, float* cnt, int* gcursor) {
  int i = blockIdx.x * blockDim.x + threadIdx.x;
  if (i < NG * H) pool[i] = 0.f;
  if (i < NG) cnt[i] = 0.f;
  if (i < NB) gcursor[i] = i * CAP;
}

// ---------- pass 1: bucket edges by dst>>8 (LDS histogram + chunk reserve) ----------
__global__ void k_bucket(const int* __restrict__ ei, int* __restrict__ gcursor,
                         unsigned* __restrict__ ebuf, int* __restrict__ dirs,
                         ushort* __restrict__ dirl) {
  __shared__ int cnt[NB];
  __shared__ int cpos[NB];
  int t = threadIdx.x, b = blockIdx.x;
  for (int j = t; j < NB; j += 256) cnt[j] = 0;
  __syncthreads();
  int e0 = b * EPB;
  for (int i = t; i < EPB; i += 256) {
    int d = ei[NE + e0 + i];
    atomicAdd(&cnt[d >> 8], 1);
  }
  __syncthreads();
  for (int j = t; j < NB; j += 256) {
    int c = cnt[j];
    int start = atomicAdd(&gcursor[j], c);
    cpos[j] = start;
    dirs[b * NB + j] = start;
    dirl[b * NB + j] = (ushort)c;
  }
  __syncthreads();
  for (int j = t; j < NB; j += 256) cnt[j] = 0;
  __syncthreads();
  for (int i = t; i < EPB; i += 256) {
    int s = ei[e0 + i];
    int d = ei[NE + e0 + i];
    int bk = d >> 8;
    int slot = cpos[bk] + atomicAdd(&cnt[bk], 1);
    ebuf[slot] = (unsigned)s | ((unsigned)(d & 255) << 17);  // src:17b | local:8b
  }
}

// ---------- tiny scan of bucket totals ----------
__global__ void k_bucketscan(const int* __restrict__ gcursor, int* __restrict__ gbase,
                             int* __restrict__ offs) {
  if (threadIdx.x == 0) {
    int run = 0;
    for (int j = 0; j < NB; ++j) {
      int tot = gcursor[j] - j * CAP;
      gbase[j] = run; run += tot;
    }
    gbase[NB] = run;
    offs[NN] = run;   // == NE
  }
}

// ---------- pass 2: per-bucket histogram/scan -> offs, dis, xs16, csr ----------
__global__ void k_csr(const unsigned* __restrict__ ebuf, const int* __restrict__ dirs,
                      const ushort* __restrict__ dirl, const int* __restrict__ gbase,
                      const float* __restrict__ x,
                      int* __restrict__ offs, float* __restrict__ dis,
                      unsigned* __restrict__ xs16, int* __restrict__ csr, int n) {
  __shared__ int histc[256];
  __shared__ int loffs[256];
  __shared__ int wps[4];
  int t = threadIdx.x, j = blockIdx.x;
  histc[t] = 0;
  __syncthreads();
  int cstart = dirs[t * NB + j];
  int clen = dirl[t * NB + j];
  for (int k = 0; k < clen; ++k) {
    unsigned u = ebuf[cstart + k];
    atomicAdd(&histc[u >> 17], 1);
  }
  __syncthreads();
  int h = histc[t];
  int inc = h;
  int lane = t & 63;
#pragma unroll
  for (int off = 1; off < 64; off <<= 1) {
    int y = __shfl_up(inc, off, 64);
    if (lane >= off) inc += y;
  }
  if (lane == 63) wps[t >> 6] = inc;
  __syncthreads();
  int woff = 0;
  for (int i = 0; i < (t >> 6); ++i) woff += wps[i];
  int excl = gbase[j] + woff + inc - h;
  loffs[t] = excl;
  int node = j * 256 + t;
  if (node < n) {
    offs[node] = excl;
    float dd = rsqrtf((float)(h + 1));
    dis[node] = dd;
    const float* xr = x + (size_t)node * 10;
#pragma unroll
    for (int q = 0; q < 8; ++q) {
      float a = (2 * q < 10) ? xr[2 * q] * dd : 0.f;
      float bb = (2 * q + 1 < 10) ? xr[2 * q + 1] * dd : 0.f;
      xs16[node * 8 + q] = bf_pack(a, bb);
    }
  }
  __syncthreads();
  for (int k = 0; k < clen; ++k) {
    unsigned u = ebuf[cstart + k];
    int src = (int)(u & 0x1FFFFu);
    int slot = atomicAdd(&loffs[u >> 17], 1);
    csr[slot] = src;
  }
}

// ---------- layer 1: gather 16-wide + dense 10x128 ----------

__global__ void k_gather16(const int* __restrict__ offs, const int* __restrict__ csr,
                           const float* __restrict__ dis, const unsigned* __restrict__ xs16,
                           float2* __restrict__ agg, int n) {
  int wid = (blockIdx.x * blockDim.x + threadIdx.x) >> 6;
  int lane = threadIdx.x & 63;
  int g = lane >> 3, sl = lane & 7;
  int node = wid * 8 + g;
  if (node >= n) return;
  unsigned self = xs16[node * 8 + sl];
  float sx = bf_lo(self), sy = bf_hi(self);
  float tx = 0.f, ty = 0.f;
  int e = offs[node], end = offs[node + 1];
  for (; e + 3 < end; e += 4) {
    int s0 = csr[e], s1 = csr[e + 1], s2 = csr[e + 2], s3 = csr[e + 3];
    unsigned u0 = xs16[s0 * 8 + sl], u1 = xs16[s1 * 8 + sl];
    unsigned u2 = xs16[s2 * 8 + sl], u3 = xs16[s3 * 8 + sl];
    sx += bf_lo(u0) + bf_lo(u1); tx += bf_lo(u2) + bf_lo(u3);
    sy += bf_hi(u0) + bf_hi(u1); ty += bf_hi(u2) + bf_hi(u3);
  }
  for (; e < end; ++e) {
    unsigned v0 = xs16[csr[e] * 8 + sl];
    sx += bf_lo(v0); sy += bf_hi(v0);
  }
  float dd = dis[node];
  float2 o; o.x = (sx + tx) * dd; o.y = (sy + ty) * dd;
  agg[node * 8 + sl] = o;
}

__global__ void k_mm16(const float* __restrict__ agg, const float* __restrict__ W1,
                       const float* __restrict__ b1, ushort* __restrict__ xbuf, int n) {
  int node = blockIdx.x;
  if (node >= n) return;
  __shared__ float as[16];
  int m = threadIdx.x;
  if (m < 16) as[m] = agg[node * 16 + m];
  __syncthreads();
  float s = 0.f;
#pragma unroll
  for (int k = 0; k < 10; ++k) s += as[k] * W1[k * H + m];
  s += b1[m];
  xbuf[node * H + m] = bf1(fmaxf(s, 0.f));
}

// ---------- W2+W3 -> A-fragment pack (bf16), layout [nt][ks][lane][j] ----------
__global__ void k_cvtW2(const float* __restrict__ W2, const float* __restrict__ W3,
                        short* __restrict__ WfragA, short* __restrict__ WfragB) {
  int i = blockIdx.x * blockDim.x + threadIdx.x;  // 32768
  const float* W = (i < 16384) ? W2 : W3;
  short* outp = (i < 16384) ? WfragA : WfragB;
  int ii = i & 16383;
  int jj = ii & 7, lane = (ii >> 3) & 63, ks = (ii >> 9) & 3, nt = ii >> 11;
  int feat = nt * 16 + (lane & 15);
  int k = ks * 32 + (lane >> 4) * 8 + jj;
  outp[ii] = (short)bf1(W[k * H + feat]);
}

// ---------- layers 2/3 dense via MFMA: hs8 = fp8( (xb @ W) * dis ) ----------
__global__ void k_mm128_mfma(const short* __restrict__ xb,     // bf16 [n][128]
                             const short* __restrict__ Wfrag,  // [8][4][64][8]
                             const float* __restrict__ dis,
                             unsigned* __restrict__ hs8, int n) {
  int t = threadIdx.x;
  int lane = t & 63, w = t >> 6;
  int nbase = blockIdx.x * 64 + w * 16;
  int node = nbase + (lane & 15);
  bool valid = node < n;
  int nc = valid ? node : (n - 1);
  short8 xf0, xf1, xf2, xf3;
  const short* xrow = xb + (size_t)nc * H + (lane >> 4) * 8;
  xf0 = *(const short8*)(xrow);
  xf1 = *(const short8*)(xrow + 32);
  xf2 = *(const short8*)(xrow + 64);
  xf3 = *(const short8*)(xrow + 96);
  float d = dis[nc];
  const short8* wf = (const short8*)Wfrag;
#pragma unroll
  for (int nt = 0; nt < 8; ++nt) {
    f32x4 acc = {0.f, 0.f, 0.f, 0.f};
    acc = __builtin_amdgcn_mfma_f32_16x16x32_bf16(wf[(nt * 4 + 0) * 64 + lane], xf0, acc, 0, 0, 0);
    acc = __builtin_amdgcn_mfma_f32_16x16x32_bf16(wf[(nt * 4 + 1) * 64 + lane], xf1, acc, 0, 0, 0);
    acc = __builtin_amdgcn_mfma_f32_16x16x32_bf16(wf[(nt * 4 + 2) * 64 + lane], xf2, acc, 0, 0, 0);
    acc = __builtin_amdgcn_mfma_f32_16x16x32_bf16(wf[(nt * 4 + 3) * 64 + lane], xf3, acc, 0, 0, 0);
    if (valid) {
      int pk = __builtin_amdgcn_cvt_pk_fp8_f32(acc[0] * d, acc[1] * d, 0, false);
      pk = __builtin_amdgcn_cvt_pk_fp8_f32(acc[2] * d, acc[3] * d, pk, true);
      hs8[node * 32 + nt * 4 + (lane >> 4)] = (unsigned)pk;
    }
  }
}

// ---------- gather 128-wide: one node per wave, TWO edges per VMEM inst ----------
// Array-free (named scalars only) so nothing can be LDS/scratch-promoted.
#define RFL(v) __builtin_amdgcn_readfirstlane(v)
#define LOADP(sa, sb) hsu[(size_t)(hihalf ? (sb) : (sa)) * 32 + q]
#define ACCU(uu) { \
    v2f lo_ = __builtin_amdgcn_cvt_pk_f32_fp8((int)(uu), false); \
    v2f hi_ = __builtin_amdgcn_cvt_pk_f32_fp8((int)(uu), true);  \
    a0 += lo_.x; a1 += lo_.y; a2 += hi_.x; a3 += hi_.y; }

template <bool RELU, bool BIAS, bool OUTBF>
__global__ void k_gather(const int* __restrict__ offs, const int* __restrict__ csr,
                         const float* __restrict__ dis, const unsigned* __restrict__ hsu,
                         const float* __restrict__ b, void* __restrict__ outp, int n) {
  int node = (blockIdx.x * blockDim.x + threadIdx.x) >> 6;
  node = RFL(node);
  int lane = threadIdx.x & 63;
  int q = lane & 31;
  bool hihalf = lane >= 32;
  if (node >= n) return;
  float a0 = 0.f, a1 = 0.f, a2 = 0.f, a3 = 0.f;
  float mhi = hihalf ? 0.f : 1.f;   // mask for half-1-absent slots
  int e = RFL(offs[node]);
  int end = RFL(offs[node + 1]);

  // prologue pair: self (half 0) + first edge (half 1, masked if absent)
  {
    bool haveB = e < end;
    int sB = haveB ? RFL(csr[e]) : node;
    unsigned u = LOADP(node, sB);
    v2f lo = __builtin_amdgcn_cvt_pk_f32_fp8((int)u, false);
    v2f hi = __builtin_amdgcn_cvt_pk_f32_fp8((int)u, true);
    if (haveB) {
      a0 += lo.x; a1 += lo.y; a2 += hi.x; a3 += hi.y;
      ++e;
    } else {
      a0 += lo.x * mhi; a1 += lo.y * mhi; a2 += hi.x * mhi; a3 += hi.y * mhi;
    }
  }

  for (; e + 15 < end; e += 16) {   // 8 pairs, fully scalar-named
    int s0 = RFL(csr[e]),      s1 = RFL(csr[e + 1]);
    int s2 = RFL(csr[e + 2]),  s3 = RFL(csr[e + 3]);
    int s4 = RFL(csr[e + 4]),  s5 = RFL(csr[e + 5]);
    int s6 = RFL(csr[e + 6]),  s7 = RFL(csr[e + 7]);
    int s8 = RFL(csr[e + 8]),  s9 = RFL(csr[e + 9]);
    int sA = RFL(csr[e + 10]), sB = RFL(csr[e + 11]);
    int sC = RFL(csr[e + 12]), sD = RFL(csr[e + 13]);
    int sE = RFL(csr[e + 14]), sF = RFL(csr[e + 15]);
    unsigned u0 = LOADP(s0, s1);
    unsigned u1 = LOADP(s2, s3);
    unsigned u2 = LOADP(s4, s5);
    unsigned u3 = LOADP(s6, s7);
    unsigned u4 = LOADP(s8, s9);
    unsigned u5 = LOADP(sA, sB);
    unsigned u6 = LOADP(sC, sD);
    unsigned u7 = LOADP(sE, sF);
    ACCU(u0); ACCU(u1); ACCU(u2); ACCU(u3);
    ACCU(u4); ACCU(u5); ACCU(u6); ACCU(u7);
  }
  if (e + 7 < end) {                // 4 pairs
    int s0 = RFL(csr[e]),     s1 = RFL(csr[e + 1]);
    int s2 = RFL(csr[e + 2]), s3 = RFL(csr[e + 3]);
    int s4 = RFL(csr[e + 4]), s5 = RFL(csr[e + 5]);
    int s6 = RFL(csr[e + 6]), s7 = RFL(csr[e + 7]);
    unsigned u0 = LOADP(s0, s1);
    unsigned u1 = LOADP(s2, s3);
    unsigned u2 = LOADP(s4, s5);
    unsigned u3 = LOADP(s6, s7);
    ACCU(u0); ACCU(u1); ACCU(u2); ACCU(u3);
    e += 8;
  }
  if (e + 3 < end) {                // 2 pairs
    int s0 = RFL(csr[e]),     s1 = RFL(csr[e + 1]);
    int s2 = RFL(csr[e + 2]), s3 = RFL(csr[e + 3]);
    unsigned u0 = LOADP(s0, s1);
    unsigned u1 = LOADP(s2, s3);
    ACCU(u0); ACCU(u1);
    e += 4;
  }
  if (e + 1 < end) {                // 1 pair
    int s0 = RFL(csr[e]), s1 = RFL(csr[e + 1]);
    unsigned u0 = LOADP(s0, s1);
    ACCU(u0);
    e += 2;
  }
  if (e < end) {                    // final single edge (half 0 only, uniform row)
    int s0 = RFL(csr[e]);
    unsigned u = hsu[(size_t)s0 * 32 + q];
    v2f lo = __builtin_amdgcn_cvt_pk_f32_fp8((int)u, false);
    v2f hi = __builtin_amdgcn_cvt_pk_f32_fp8((int)u, true);
    a0 += lo.x * mhi; a1 += lo.y * mhi; a2 += hi.x * mhi; a3 += hi.y * mhi;
  }

  // merge halves via ds_bpermute lane^32 (no LDS allocation)
  a0 += swap32(a0);
  a1 += swap32(a1);
  a2 += swap32(a2);
  a3 += swap32(a3);

  if (!hihalf) {
    float dd = dis[node];
    float v0 = a0 * dd, v1 = a1 * dd, v2 = a2 * dd, v3 = a3 * dd;
    if (BIAS) {
      float4 bb = ((const float4*)b)[q];
      v0 += bb.x; v1 += bb.y; v2 += bb.z; v3 += bb.w;
    }
    if (RELU) {
      v0 = fmaxf(v0, 0.f); v1 = fmaxf(v1, 0.f);
      v2 = fmaxf(v2, 0.f); v3 = fmaxf(v3, 0.f);
    }
    if (OUTBF) {
      uint2 o;
      o.x = bf_pack(v0, v1);
      o.y = bf_pack(v2, v3);
      ((uint2*)outp)[(size_t)node * 32 + q] = o;
    } else {
      float4 o; o.x = v0; o.y = v1; o.z = v2; o.w = v3;
      ((float4*)outp)[(size_t)node * 32 + q] = o;
    }
  }
}

// ---------- pooling / output ----------

// acc is bf16 [n][128]
__global__ void k_pool(const ushort* __restrict__ acc, const float* __restrict__ b3,
                       const int* __restrict__ batch, float* pool, float* cnt, int n) {
  int m = threadIdx.x;
  int n0 = blockIdx.x * 64;
  float run = 0.f, crun = 0.f;
  int curg = -1;
  float bm = b3[m];
  for (int i = 0; i < 64; ++i) {
    int node = n0 + i;
    if (node >= n) break;
    int g = batch[node];
    if (g != curg) {
      if (curg >= 0) {
        atomicAdd(&pool[curg * H + m], run);
        if (m == 0) atomicAdd(&cnt[curg], crun);
      }
      curg = g; run = 0.f; crun = 0.f;
    }
    run += __uint_as_float((unsigned)acc[node * H + m] << 16) + bm;
    crun += 1.f;
  }
  if (curg >= 0) {
    atomicAdd(&pool[curg * H + m], run);
    if (m == 0) atomicAdd(&cnt[curg], crun);
  }
}

__global__ void k_out(const float* __restrict__ pool, const float* __restrict__ cnt,
                      const float* __restrict__ Wlin, const float* __restrict__ blin,
                      float* __restrict__ out) {
  int t = threadIdx.x;
  if (t >= NG * 3) return;
  int g = t / 3, c = t % 3;
  float invc = 1.f / fmaxf(cnt[g], 1.f);
  float s = 0.f;
  for (int m = 0; m < H; ++m) s += pool[g * H + m] * Wlin[m * 3 + c];
  out[t] = s * invc + blin[c];
}

extern "C" void kernel_launch(void* const* d_in, const int* in_sizes, int n_in,
                              void* d_out, int out_size, void* d_ws, size_t ws_size,
                              hipStream_t stream) {
  const float* x     = (const float*)d_in[0];
  const int*   ei    = (const int*)d_in[1];
  const int*   batch = (const int*)d_in[2];
  const float* W1    = (const float*)d_in[3];
  const float* b1    = (const float*)d_in[4];
  const float* W2    = (const float*)d_in[5];
  const float* b2    = (const float*)d_in[6];
  const float* W3    = (const float*)d_in[7];
  const float* b3    = (const float*)d_in[8];
  const float* Wlin  = (const float*)d_in[9];
  const float* blin  = (const float*)d_in[10];
  float* out = (float*)d_out;

  char* ws = (char*)d_ws;
  float*    dis    = (float*)ws;     ws += sizeof(float) * NN;
  unsigned* hs8    = (unsigned*)ws;  ws += (size_t)NN * H;                  // fp8
  ushort*   xbuf   = (ushort*)ws;    ws += sizeof(ushort) * (size_t)NN * H; // bf16
  short*    WfragA = (short*)ws;     ws += sizeof(short) * 16384;
  short*    WfragB = (short*)ws;     ws += sizeof(short) * 16384;
  unsigned* xs16   = (unsigned*)ws;  ws += sizeof(unsigned) * (size_t)NN * 8;
  float*    agg    = (float*)ws;     ws += sizeof(float) * (size_t)NN * 16;
  float*    pool   = (float*)ws;     ws += sizeof(float) * NG * H;
  float*    cnt    = (float*)ws;     ws += sizeof(float) * NG;
  int*      offs   = (int*)ws;       ws += sizeof(int) * (NN + 8);
  int*      csr    = (int*)ws;       ws += sizeof(int) * NE;
  unsigned* ebuf   = (unsigned*)ws;  ws += sizeof(unsigned) * (size_t)NB * CAP;
  int*      dirs   = (int*)ws;       ws += sizeof(int) * P1B * NB;
  ushort*   dirl   = (ushort*)ws;    ws += sizeof(ushort) * P1B * NB;
  int*      gcur   = (int*)ws;       ws += sizeof(int) * NB;
  int*      gbase  = (int*)ws;       ws += sizeof(int) * (NB + 1);

  // CSR build: LDS-bucketed counting sort (no fine-grained device atomics)
  k_init<<<32, 256, 0, stream>>>(pool, cnt, gcur);
  k_bucket<<<P1B, 256, 0, stream>>>(ei, gcur, ebuf, dirs, dirl);
  k_bucketscan<<<1, 64, 0, stream>>>(gcur, gbase, offs);
  k_csr<<<NB, 256, 0, stream>>>(ebuf, dirs, dirl, gbase, x, offs, dis, xs16, csr, NN);
  k_cvtW2<<<128, 256, 0, stream>>>(W2, W3, WfragA, WfragB);

  const int GATHER_GRID = (NN + 3) / 4;   // 1 node/wave, 4 waves/block
  const int MM_GRID = (NN + 63) / 64;     // 64 nodes/block (16/wave)

  // layer 1: aggregate-first (A·X)·W1
  k_gather16<<<(NN + 31) / 32, 256, 0, stream>>>(offs, csr, dis, xs16, (float2*)agg, NN);
  k_mm16<<<NN, 128, 0, stream>>>(agg, W1, b1, xbuf, NN);

  // layer 2
  k_mm128_mfma<<<MM_GRID, 256, 0, stream>>>((const short*)xbuf, WfragA, dis, hs8, NN);
  k_gather<true, true, true><<<GATHER_GRID, 256, 0, stream>>>(
      offs, csr, dis, hs8, b2, xbuf, NN);

  // layer 3
  k_mm128_mfma<<<MM_GRID, 256, 0, stream>>>((const short*)xbuf, WfragB, dis, hs8, NN);
  k_gather<false, false, true><<<GATHER_GRID, 256, 0, stream>>>(
      offs, csr, dis, hs8, nullptr, xbuf, NN);

  // pool + head
  k_pool<<<(NN + 63) / 64, 128, 0, stream>>>(xbuf, b3, batch, pool, cnt, NN);
  k_out<<<1, 256, 0, stream>>>(pool, cnt, Wlin, blin, out);
}

// Round 15
// 230.873 us; speedup vs baseline: 2.1756x; 1.1408x over previous
//
#include <hip/hip_runtime.h>

constexpr int NN = 100000;
constexpr int NE = 1600000;
constexpr int NG = 64;
constexpr int H  = 128;

constexpr int NB  = 392;       // dst buckets (dst >> 8, 256 nodes each)
constexpr int CAP = 5120;      // ebuf capacity per bucket (mean 4082, sigma ~64)
constexpr int P1B = 256;       // pass-1 blocks
constexpr int EPB = NE / P1B;  // 6250 edges per pass-1 block

typedef float v2f   __attribute__((ext_vector_type(2)));
typedef float f32x4 __attribute__((ext_vector_type(4)));
typedef short short8 __attribute__((ext_vector_type(8)));

// ---------- bf16 helpers ----------
__device__ __forceinline__ float bf_lo(unsigned v) { return __uint_as_float(v << 16); }
__device__ __forceinline__ float bf_hi(unsigned v) { return __uint_as_float(v & 0xffff0000u); }
__device__ __forceinline__ unsigned bf_pack(float a, float b) {  // RTNE
  unsigned ua = __float_as_uint(a);
  unsigned ub = __float_as_uint(b);
  ua += 0x7fffu + ((ua >> 16) & 1u);
  ub += 0x7fffu + ((ub >> 16) & 1u);
  return (ua >> 16) | (ub & 0xffff0000u);
}
__device__ __forceinline__ ushort bf1(float a) {
  unsigned u = __float_as_uint(a);
  u += 0x7fffu + ((u >> 16) & 1u);
  return (ushort)(u >> 16);
}

// lane ^ 32 exchange via ds_bpermute (no LDS allocation)
__device__ __forceinline__ float swap32(float v) {
  int idx = (((int)threadIdx.x & 63) ^ 32) << 2;
  return __int_as_float(__builtin_amdgcn_ds_bpermute(idx, __float_as_int(v)));
}

// ---------- fused init + W2/W3 fragment pack ----------
__global__ void k_cvtinit(const float* __restrict__ W2, const float* __restrict__ W3,
                          short* __restrict__ WfragA, short* __restrict__ WfragB,
                          float* pool, float* cnt, int* gcursor) {
  int i = blockIdx.x * blockDim.x + threadIdx.x;  // 32768
  if (i < NG * H) pool[i] = 0.f;
  if (i < NG) cnt[i] = 0.f;
  if (i < NB) gcursor[i] = i * CAP;
  const float* W = (i < 16384) ? W2 : W3;
  short* outp = (i < 16384) ? WfragA : WfragB;
  int ii = i & 16383;
  int jj = ii & 7, lane = (ii >> 3) & 63, ks = (ii >> 9) & 3, nt = ii >> 11;
  int feat = nt * 16 + (lane & 15);
  int k = ks * 32 + (lane >> 4) * 8 + jj;
  outp[ii] = (short)bf1(W[k * H + feat]);
}

// ---------- pass 1: bucket edges by dst>>8 (LDS histogram + chunk reserve) ----------
__global__ void k_bucket(const int* __restrict__ ei, int* __restrict__ gcursor,
                         unsigned* __restrict__ ebuf, int* __restrict__ dirs,
                         ushort* __restrict__ dirl) {
  __shared__ int cnt[NB];
  __shared__ int cpos[NB];
  int t = threadIdx.x, b = blockIdx.x;
  for (int j = t; j < NB; j += 256) cnt[j] = 0;
  __syncthreads();
  int e0 = b * EPB;
  const int2* d2 = (const int2*)&ei[NE + e0];   // e0 even -> 8B aligned
  const int2* s2 = (const int2*)&ei[e0];
  for (int i2 = t; i2 < EPB / 2; i2 += 256) {
    int2 dv = d2[i2];
    atomicAdd(&cnt[dv.x >> 8], 1);
    atomicAdd(&cnt[dv.y >> 8], 1);
  }
  __syncthreads();
  for (int j = t; j < NB; j += 256) {
    int c = cnt[j];
    int start = atomicAdd(&gcursor[j], c);
    cpos[j] = start;
    dirs[b * NB + j] = start;
    dirl[b * NB + j] = (ushort)c;
  }
  __syncthreads();
  for (int j = t; j < NB; j += 256) cnt[j] = 0;
  __syncthreads();
  for (int i2 = t; i2 < EPB / 2; i2 += 256) {
    int2 sv = s2[i2];
    int2 dv = d2[i2];
    int bk0 = dv.x >> 8;
    int slot0 = cpos[bk0] + atomicAdd(&cnt[bk0], 1);
    ebuf[slot0] = (unsigned)sv.x | ((unsigned)(dv.x & 255) << 17);
    int bk1 = dv.y >> 8;
    int slot1 = cpos[bk1] + atomicAdd(&cnt[bk1], 1);
    ebuf[slot1] = (unsigned)sv.y | ((unsigned)(dv.y & 255) << 17);
  }
}

// ---------- parallel scan of bucket totals (1 block, 512 threads) ----------
__global__ void k_bucketscan(const int* __restrict__ gcursor, int* __restrict__ gbase,
                             int* __restrict__ offs) {
  __shared__ int ws[8];
  int t = threadIdx.x;
  int v = (t < NB) ? (gcursor[t] - t * CAP) : 0;
  int lane = t & 63, w = t >> 6;
  int inc = v;
#pragma unroll
  for (int off = 1; off < 64; off <<= 1) {
    int y = __shfl_up(inc, off, 64);
    if (lane >= off) inc += y;
  }
  if (lane == 63) ws[w] = inc;
  __syncthreads();
  int woff = 0;
  for (int i = 0; i < w; ++i) woff += ws[i];
  if (t < NB) gbase[t] = woff + inc - v;
  if (t == NB - 1) {
    gbase[NB] = woff + inc;
    offs[NN] = woff + inc;   // == NE
  }
}

// ---------- pass 2: LDS-staged per-bucket histogram/scan -> offs, dis, xs16, csr ----------
__global__ void k_csr(const unsigned* __restrict__ ebuf, const int* __restrict__ dirs,
                      const ushort* __restrict__ dirl, const int* __restrict__ gbase,
                      const int* __restrict__ gcur, const float* __restrict__ x,
                      int* __restrict__ offs, float* __restrict__ dis,
                      unsigned* __restrict__ xs16, int* __restrict__ csr, int n) {
  __shared__ unsigned sh[CAP];
  __shared__ int histc[256];
  __shared__ int loffs[256];
  __shared__ int wps[4];
  int t = threadIdx.x, j = blockIdx.x;
  int used = gcur[j] - j * CAP;
  for (int k = t; k < used; k += 256) sh[k] = ebuf[j * CAP + k];  // coalesced stage
  histc[t] = 0;
  __syncthreads();
  int rel = dirs[t * NB + j] - j * CAP;
  int clen = dirl[t * NB + j];
  for (int k = 0; k < clen; ++k) {
    atomicAdd(&histc[sh[rel + k] >> 17], 1);
  }
  __syncthreads();
  int h = histc[t];
  int inc = h;
  int lane = t & 63;
#pragma unroll
  for (int off = 1; off < 64; off <<= 1) {
    int y = __shfl_up(inc, off, 64);
    if (lane >= off) inc += y;
  }
  if (lane == 63) wps[t >> 6] = inc;
  __syncthreads();
  int woff = 0;
  for (int i = 0; i < (t >> 6); ++i) woff += wps[i];
  int excl = gbase[j] + woff + inc - h;
  loffs[t] = excl;
  int node = j * 256 + t;
  if (node < n) {
    offs[node] = excl;
    float dd = rsqrtf((float)(h + 1));
    dis[node] = dd;
    const float* xr = x + (size_t)node * 10;
#pragma unroll
    for (int q = 0; q < 8; ++q) {
      float a = (2 * q < 10) ? xr[2 * q] * dd : 0.f;
      float bb = (2 * q + 1 < 10) ? xr[2 * q + 1] * dd : 0.f;
      xs16[node * 8 + q] = bf_pack(a, bb);
    }
  }
  __syncthreads();
  for (int k = 0; k < clen; ++k) {
    unsigned u = sh[rel + k];
    int src = (int)(u & 0x1FFFFu);
    int slot = atomicAdd(&loffs[u >> 17], 1);
    csr[slot] = src;
  }
}

// ---------- layer 1: gather 16-wide + batched dense 10x128 ----------

__global__ void k_gather16(const int* __restrict__ offs, const int* __restrict__ csr,
                           const float* __restrict__ dis, const unsigned* __restrict__ xs16,
                           float2* __restrict__ agg, int n) {
  int wid = (blockIdx.x * blockDim.x + threadIdx.x) >> 6;
  int lane = threadIdx.x & 63;
  int g = lane >> 3, sl = lane & 7;
  int node = wid * 8 + g;
  if (node >= n) return;
  unsigned self = xs16[node * 8 + sl];
  float sx = bf_lo(self), sy = bf_hi(self);
  float tx = 0.f, ty = 0.f;
  int e = offs[node], end = offs[node + 1];
  for (; e + 3 < end; e += 4) {
    int s0 = csr[e], s1 = csr[e + 1], s2 = csr[e + 2], s3 = csr[e + 3];
    unsigned u0 = xs16[s0 * 8 + sl], u1 = xs16[s1 * 8 + sl];
    unsigned u2 = xs16[s2 * 8 + sl], u3 = xs16[s3 * 8 + sl];
    sx += bf_lo(u0) + bf_lo(u1); tx += bf_lo(u2) + bf_lo(u3);
    sy += bf_hi(u0) + bf_hi(u1); ty += bf_hi(u2) + bf_hi(u3);
  }
  for (; e < end; ++e) {
    unsigned v0 = xs16[csr[e] * 8 + sl];
    sx += bf_lo(v0); sy += bf_hi(v0);
  }
  float dd = dis[node];
  float2 o; o.x = (sx + tx) * dd; o.y = (sy + ty) * dd;
  agg[node * 8 + sl] = o;
}

// 16 nodes/block: agg staged in LDS, W1 column in registers
__global__ void k_mm16(const float* __restrict__ agg, const float* __restrict__ W1,
                       const float* __restrict__ b1, ushort* __restrict__ xbuf, int n) {
  __shared__ float as[16][16];
  int t = threadIdx.x;
  int n0 = blockIdx.x * 16;
  int lnode = t >> 4;
  int node = n0 + lnode;
  float v = (node < n) ? agg[(size_t)node * 16 + (t & 15)] : 0.f;
  as[lnode][t & 15] = v;
  __syncthreads();
  int m = t & 127;
  int half = t >> 7;   // 0 or 1 -> nodes 0-7 / 8-15
  float w0 = W1[0 * H + m], w1 = W1[1 * H + m], w2 = W1[2 * H + m];
  float w3 = W1[3 * H + m], w4 = W1[4 * H + m], w5 = W1[5 * H + m];
  float w6 = W1[6 * H + m], w7 = W1[7 * H + m], w8 = W1[8 * H + m];
  float w9 = W1[9 * H + m];
  float bm = b1[m];
#pragma unroll
  for (int j = 0; j < 8; ++j) {
    int nl = half * 8 + j;
    int nd = n0 + nl;
    if (nd < n) {
      float s = bm;
      s += as[nl][0] * w0 + as[nl][1] * w1 + as[nl][2] * w2 + as[nl][3] * w3;
      s += as[nl][4] * w4 + as[nl][5] * w5 + as[nl][6] * w6 + as[nl][7] * w7;
      s += as[nl][8] * w8 + as[nl][9] * w9;
      xbuf[(size_t)nd * H + m] = bf1(fmaxf(s, 0.f));
    }
  }
}

// ---------- layers 2/3 dense via MFMA: hs8 = fp8( (xb @ W) * dis ) ----------
__global__ void k_mm128_mfma(const short* __restrict__ xb,     // bf16 [n][128]
                             const short* __restrict__ Wfrag,  // [8][4][64][8]
                             const float* __restrict__ dis,
                             unsigned* __restrict__ hs8, int n) {
  int t = threadIdx.x;
  int lane = t & 63, w = t >> 6;
  int nbase = blockIdx.x * 64 + w * 16;
  int node = nbase + (lane & 15);
  bool valid = node < n;
  int nc = valid ? node : (n - 1);
  short8 xf0, xf1, xf2, xf3;
  const short* xrow = xb + (size_t)nc * H + (lane >> 4) * 8;
  xf0 = *(const short8*)(xrow);
  xf1 = *(const short8*)(xrow + 32);
  xf2 = *(const short8*)(xrow + 64);
  xf3 = *(const short8*)(xrow + 96);
  float d = dis[nc];
  const short8* wf = (const short8*)Wfrag;
#pragma unroll
  for (int nt = 0; nt < 8; ++nt) {
    f32x4 acc = {0.f, 0.f, 0.f, 0.f};
    acc = __builtin_amdgcn_mfma_f32_16x16x32_bf16(wf[(nt * 4 + 0) * 64 + lane], xf0, acc, 0, 0, 0);
    acc = __builtin_amdgcn_mfma_f32_16x16x32_bf16(wf[(nt * 4 + 1) * 64 + lane], xf1, acc, 0, 0, 0);
    acc = __builtin_amdgcn_mfma_f32_16x16x32_bf16(wf[(nt * 4 + 2) * 64 + lane], xf2, acc, 0, 0, 0);
    acc = __builtin_amdgcn_mfma_f32_16x16x32_bf16(wf[(nt * 4 + 3) * 64 + lane], xf3, acc, 0, 0, 0);
    if (valid) {
      int pk = __builtin_amdgcn_cvt_pk_fp8_f32(acc[0] * d, acc[1] * d, 0, false);
      pk = __builtin_amdgcn_cvt_pk_fp8_f32(acc[2] * d, acc[3] * d, pk, true);
      hs8[node * 32 + nt * 4 + (lane >> 4)] = (unsigned)pk;
    }
  }
}

// ---------- gather 128-wide: one node per wave, TWO edges per VMEM inst ----------
// Array-free (named scalars only) so nothing can be LDS/scratch-promoted.
#define RFL(v) __builtin_amdgcn_readfirstlane(v)
#define LOADP(sa, sb) hsu[(size_t)(hihalf ? (sb) : (sa)) * 32 + q]
#define ACCU(uu) { \
    v2f lo_ = __builtin_amdgcn_cvt_pk_f32_fp8((int)(uu), false); \
    v2f hi_ = __builtin_amdgcn_cvt_pk_f32_fp8((int)(uu), true);  \
    a0 += lo_.x; a1 += lo_.y; a2 += hi_.x; a3 += hi_.y; }

template <bool RELU, bool BIAS, bool OUTBF>
__global__ void k_gather(const int* __restrict__ offs, const int* __restrict__ csr,
                         const float* __restrict__ dis, const unsigned* __restrict__ hsu,
                         const float* __restrict__ b, void* __restrict__ outp, int n) {
  int node = (blockIdx.x * blockDim.x + threadIdx.x) >> 6;
  node = RFL(node);
  int lane = threadIdx.x & 63;
  int q = lane & 31;
  bool hihalf = lane >= 32;
  if (node >= n) return;
  float a0 = 0.f, a1 = 0.f, a2 = 0.f, a3 = 0.f;
  float mhi = hihalf ? 0.f : 1.f;   // mask for half-1-absent slots
  int e = RFL(offs[node]);
  int end = RFL(offs[node + 1]);

  // prologue pair: self (half 0) + first edge (half 1, masked if absent)
  {
    bool haveB = e < end;
    int sB = haveB ? RFL(csr[e]) : node;
    unsigned u = LOADP(node, sB);
    v2f lo = __builtin_amdgcn_cvt_pk_f32_fp8((int)u, false);
    v2f hi = __builtin_amdgcn_cvt_pk_f32_fp8((int)u, true);
    if (haveB) {
      a0 += lo.x; a1 += lo.y; a2 += hi.x; a3 += hi.y;
      ++e;
    } else {
      a0 += lo.x * mhi; a1 += lo.y * mhi; a2 += hi.x * mhi; a3 += hi.y * mhi;
    }
  }

  for (; e + 15 < end; e += 16) {   // 8 pairs, fully scalar-named
    int s0 = RFL(csr[e]),      s1 = RFL(csr[e + 1]);
    int s2 = RFL(csr[e + 2]),  s3 = RFL(csr[e + 3]);
    int s4 = RFL(csr[e + 4]),  s5 = RFL(csr[e + 5]);
    int s6 = RFL(csr[e + 6]),  s7 = RFL(csr[e + 7]);
    int s8 = RFL(csr[e + 8]),  s9 = RFL(csr[e + 9]);
    int sA = RFL(csr[e + 10]), sB = RFL(csr[e + 11]);
    int sC = RFL(csr[e + 12]), sD = RFL(csr[e + 13]);
    int sE = RFL(csr[e + 14]), sF = RFL(csr[e + 15]);
    unsigned u0 = LOADP(s0, s1);
    unsigned u1 = LOADP(s2, s3);
    unsigned u2 = LOADP(s4, s5);
    unsigned u3 = LOADP(s6, s7);
    unsigned u4 = LOADP(s8, s9);
    unsigned u5 = LOADP(sA, sB);
    unsigned u6 = LOADP(sC, sD);
    unsigned u7 = LOADP(sE, sF);
    ACCU(u0); ACCU(u1); ACCU(u2); ACCU(u3);
    ACCU(u4); ACCU(u5); ACCU(u6); ACCU(u7);
  }
  if (e + 7 < end) {                // 4 pairs
    int s0 = RFL(csr[e]),     s1 = RFL(csr[e + 1]);
    int s2 = RFL(csr[e + 2]), s3 = RFL(csr[e + 3]);
    int s4 = RFL(csr[e + 4]), s5 = RFL(csr[e + 5]);
    int s6 = RFL(csr[e + 6]), s7 = RFL(csr[e + 7]);
    unsigned u0 = LOADP(s0, s1);
    unsigned u1 = LOADP(s2, s3);
    unsigned u2 = LOADP(s4, s5);
    unsigned u3 = LOADP(s6, s7);
    ACCU(u0); ACCU(u1); ACCU(u2); ACCU(u3);
    e += 8;
  }
  if (e + 3 < end) {                // 2 pairs
    int s0 = RFL(csr[e]),     s1 = RFL(csr[e + 1]);
    int s2 = RFL(csr[e + 2]), s3 = RFL(csr[e + 3]);
    unsigned u0 = LOADP(s0, s1);
    unsigned u1 = LOADP(s2, s3);
    ACCU(u0); ACCU(u1);
    e += 4;
  }
  if (e + 1 < end) {                // 1 pair
    int s0 = RFL(csr[e]), s1 = RFL(csr[e + 1]);
    unsigned u0 = LOADP(s0, s1);
    ACCU(u0);
    e += 2;
  }
  if (e < end) {                    // final single edge (half 0 only, uniform row)
    int s0 = RFL(csr[e]);
    unsigned u = hsu[(size_t)s0 * 32 + q];
    v2f lo = __builtin_amdgcn_cvt_pk_f32_fp8((int)u, false);
    v2f hi = __builtin_amdgcn_cvt_pk_f32_fp8((int)u, true);
    a0 += lo.x * mhi; a1 += lo.y * mhi; a2 += hi.x * mhi; a3 += hi.y * mhi;
  }

  // merge halves via ds_bpermute lane^32 (no LDS allocation)
  a0 += swap32(a0);
  a1 += swap32(a1);
  a2 += swap32(a2);
  a3 += swap32(a3);

  if (!hihalf) {
    float dd = dis[node];
    float v0 = a0 * dd, v1 = a1 * dd, v2 = a2 * dd, v3 = a3 * dd;
    if (BIAS) {
      float4 bb = ((const float4*)b)[q];
      v0 += bb.x; v1 += bb.y; v2 += bb.z; v3 += bb.w;
    }
    if (RELU) {
      v0 = fmaxf(v0, 0.f); v1 = fmaxf(v1, 0.f);
      v2 = fmaxf(v2, 0.f); v3 = fmaxf(v3, 0.f);
    }
    if (OUTBF) {
      uint2 o;
      o.x = bf_pack(v0, v1);
      o.y = bf_pack(v2, v3);
      ((uint2*)outp)[(size_t)node * 32 + q] = o;
    } else {
      float4 o; o.x = v0; o.y = v1; o.z = v2; o.w = v3;
      ((float4*)outp)[(size_t)node * 32 + q] = o;
    }
  }
}

// ---------- pooling / output ----------

// acc is bf16 [n][128]
__global__ void k_pool(const ushort* __restrict__ acc, const float* __restrict__ b3,
                       const int* __restrict__ batch, float* pool, float* cnt, int n) {
  int m = threadIdx.x;
  int n0 = blockIdx.x * 64;
  float run = 0.f, crun = 0.f;
  int curg = -1;
  float bm = b3[m];
  for (int i = 0; i < 64; ++i) {
    int node = n0 + i;
    if (node >= n) break;
    int g = batch[node];
    if (g != curg) {
      if (curg >= 0) {
        atomicAdd(&pool[curg * H + m], run);
        if (m == 0) atomicAdd(&cnt[curg], crun);
      }
      curg = g; run = 0.f; crun = 0.f;
    }
    run += __uint_as_float((unsigned)acc[node * H + m] << 16) + bm;
    crun += 1.f;
  }
  if (curg >= 0) {
    atomicAdd(&pool[curg * H + m], run);
    if (m == 0) atomicAdd(&cnt[curg], crun);
  }
}

__global__ void k_out(const float* __restrict__ pool, const float* __restrict__ cnt,
                      const float* __restrict__ Wlin, const float* __restrict__ blin,
                      float* __restrict__ out) {
  int t = threadIdx.x;
  if (t >= NG * 3) return;
  int g = t / 3, c = t % 3;
  float invc = 1.f / fmaxf(cnt[g], 1.f);
  float s = 0.f;
  for (int m = 0; m < H; ++m) s += pool[g * H + m] * Wlin[m * 3 + c];
  out[t] = s * invc + blin[c];
}

extern "C" void kernel_launch(void* const* d_in, const int* in_sizes, int n_in,
                              void* d_out, int out_size, void* d_ws, size_t ws_size,
                              hipStream_t stream) {
  const float* x     = (const float*)d_in[0];
  const int*   ei    = (const int*)d_in[1];
  const int*   batch = (const int*)d_in[2];
  const float* W1    = (const float*)d_in[3];
  const float* b1    = (const float*)d_in[4];
  const float* W2    = (const float*)d_in[5];
  const float* b2    = (const float*)d_in[6];
  const float* W3    = (const float*)d_in[7];
  const float* b3    = (const float*)d_in[8];
  const float* Wlin  = (const float*)d_in[9];
  const float* blin  = (const float*)d_in[10];
  float* out = (float*)d_out;

  char* ws = (char*)d_ws;
  float*    dis    = (float*)ws;     ws += sizeof(float) * NN;
  unsigned* hs8    = (unsigned*)ws;  ws += (size_t)NN * H;                  // fp8
  ushort*   xbuf   = (ushort*)ws;    ws += sizeof(ushort) * (size_t)NN * H; // bf16
  short*    WfragA = (short*)ws;     ws += sizeof(short) * 16384;
  short*    WfragB = (short*)ws;     ws += sizeof(short) * 16384;
  unsigned* xs16   = (unsigned*)ws;  ws += sizeof(unsigned) * (size_t)NN * 8;
  float*    agg    = (float*)ws;     ws += sizeof(float) * (size_t)NN * 16;
  float*    pool   = (float*)ws;     ws += sizeof(float) * NG * H;
  float*    cnt    = (float*)ws;     ws += sizeof(float) * NG;
  int*      offs   = (int*)ws;       ws += sizeof(int) * (NN + 8);
  int*      csr    = (int*)ws;       ws += sizeof(int) * NE;
  unsigned* ebuf   = (unsigned*)ws;  ws += sizeof(unsigned) * (size_t)NB * CAP;
  int*      dirs   = (int*)ws;       ws += sizeof(int) * P1B * NB;
  ushort*   dirl   = (ushort*)ws;    ws += sizeof(ushort) * P1B * NB;
  int*      gcur   = (int*)ws;       ws += sizeof(int) * NB;
  int*      gbase  = (int*)ws;       ws += sizeof(int) * (NB + 1);

  // init + W pack (fused), then CSR build: LDS-bucketed counting sort
  k_cvtinit<<<128, 256, 0, stream>>>(W2, W3, WfragA, WfragB, pool, cnt, gcur);
  k_bucket<<<P1B, 256, 0, stream>>>(ei, gcur, ebuf, dirs, dirl);
  k_bucketscan<<<1, 512, 0, stream>>>(gcur, gbase, offs);
  k_csr<<<NB, 256, 0, stream>>>(ebuf, dirs, dirl, gbase, gcur, x, offs, dis, xs16, csr, NN);

  const int GATHER_GRID = (NN + 3) / 4;   // 1 node/wave, 4 waves/block
  const int MM_GRID = (NN + 63) / 64;     // 64 nodes/block (16/wave)

  // layer 1: aggregate-first (A·X)·W1
  k_gather16<<<(NN + 31) / 32, 256, 0, stream>>>(offs, csr, dis, xs16, (float2*)agg, NN);
  k_mm16<<<(NN + 15) / 16, 256, 0, stream>>>(agg, W1, b1, xbuf, NN);

  // layer 2
  k_mm128_mfma<<<MM_GRID, 256, 0, stream>>>((const short*)xbuf, WfragA, dis, hs8, NN);
  k_gather<true, true, true><<<GATHER_GRID, 256, 0, stream>>>(
      offs, csr, dis, hs8, b2, xbuf, NN);

  // layer 3
  k_mm128_mfma<<<MM_GRID, 256, 0, stream>>>((const short*)xbuf, WfragB, dis, hs8, NN);
  k_gather<false, false, true><<<GATHER_GRID, 256, 0, stream>>>(
      offs, csr, dis, hs8, nullptr, xbuf, NN);

  // pool + head
  k_pool<<<(NN + 63) / 64, 128, 0, stream>>>(xbuf, b3, batch, pool, cnt, NN);
  k_out<<<1, 256, 0, stream>>>(pool, cnt, Wlin, blin, out);
}

// Round 16
// 229.915 us; speedup vs baseline: 2.1846x; 1.0042x over previous
//
#include <hip/hip_runtime.h>

constexpr int NN = 100000;
constexpr int NE = 1600000;
constexpr int NG = 64;
constexpr int H  = 128;

constexpr int NB  = 392;       // dst buckets (dst >> 8, 256 nodes each)
constexpr int CAP = 5120;      // ebuf capacity per bucket (mean 4082, sigma ~64)
constexpr int P1B = 256;       // pass-1 blocks
constexpr int EPB = NE / P1B;  // 6250 edges per pass-1 block

typedef float v2f   __attribute__((ext_vector_type(2)));
typedef float f32x4 __attribute__((ext_vector_type(4)));
typedef short short8 __attribute__((ext_vector_type(8)));

// ---------- bf16 helpers ----------
__device__ __forceinline__ float bf_lo(unsigned v) { return __uint_as_float(v << 16); }
__device__ __forceinline__ float bf_hi(unsigned v) { return __uint_as_float(v & 0xffff0000u); }
__device__ __forceinline__ unsigned bf_pack(float a, float b) {  // RTNE
  unsigned ua = __float_as_uint(a);
  unsigned ub = __float_as_uint(b);
  ua += 0x7fffu + ((ua >> 16) & 1u);
  ub += 0x7fffu + ((ub >> 16) & 1u);
  return (ua >> 16) | (ub & 0xffff0000u);
}
__device__ __forceinline__ ushort bf1(float a) {
  unsigned u = __float_as_uint(a);
  u += 0x7fffu + ((u >> 16) & 1u);
  return (ushort)(u >> 16);
}

// lane ^ 32 exchange via ds_bpermute (no LDS allocation)
__device__ __forceinline__ float swap32(float v) {
  int idx = (((int)threadIdx.x & 63) ^ 32) << 2;
  return __int_as_float(__builtin_amdgcn_ds_bpermute(idx, __float_as_int(v)));
}

// ---------- fused init + W2/W3 fragment pack ----------
__global__ void k_cvtinit(const float* __restrict__ W2, const float* __restrict__ W3,
                          short* __restrict__ WfragA, short* __restrict__ WfragB,
                          float* pool, float* cnt, int* gcursor) {
  int i = blockIdx.x * blockDim.x + threadIdx.x;  // 32768
  if (i < NG * H) pool[i] = 0.f;
  if (i < NG) cnt[i] = 0.f;
  if (i < NB) gcursor[i] = i * CAP;
  const float* W = (i < 16384) ? W2 : W3;
  short* outp = (i < 16384) ? WfragA : WfragB;
  int ii = i & 16383;
  int jj = ii & 7, lane = (ii >> 3) & 63, ks = (ii >> 9) & 3, nt = ii >> 11;
  int feat = nt * 16 + (lane & 15);
  int k = ks * 32 + (lane >> 4) * 8 + jj;
  outp[ii] = (short)bf1(W[k * H + feat]);
}

// ---------- pass 1: bucket edges by dst>>8 (LDS histogram + chunk reserve) ----------
__global__ void k_bucket(const int* __restrict__ ei, int* __restrict__ gcursor,
                         unsigned* __restrict__ ebuf, int* __restrict__ dirs,
                         ushort* __restrict__ dirl) {
  __shared__ int cnt[NB];
  __shared__ int cpos[NB];
  int t = threadIdx.x, b = blockIdx.x;
  for (int j = t; j < NB; j += 256) cnt[j] = 0;
  __syncthreads();
  int e0 = b * EPB;
  const int2* d2 = (const int2*)&ei[NE + e0];   // e0 even -> 8B aligned
  const int2* s2 = (const int2*)&ei[e0];
  for (int i2 = t; i2 < EPB / 2; i2 += 256) {
    int2 dv = d2[i2];
    atomicAdd(&cnt[dv.x >> 8], 1);
    atomicAdd(&cnt[dv.y >> 8], 1);
  }
  __syncthreads();
  for (int j = t; j < NB; j += 256) {
    int c = cnt[j];
    int start = atomicAdd(&gcursor[j], c);
    cpos[j] = start;
    dirs[b * NB + j] = start;
    dirl[b * NB + j] = (ushort)c;
  }
  __syncthreads();
  for (int j = t; j < NB; j += 256) cnt[j] = 0;
  __syncthreads();
  for (int i2 = t; i2 < EPB / 2; i2 += 256) {
    int2 sv = s2[i2];
    int2 dv = d2[i2];
    int bk0 = dv.x >> 8;
    int slot0 = cpos[bk0] + atomicAdd(&cnt[bk0], 1);
    ebuf[slot0] = (unsigned)sv.x | ((unsigned)(dv.x & 255) << 17);
    int bk1 = dv.y >> 8;
    int slot1 = cpos[bk1] + atomicAdd(&cnt[bk1], 1);
    ebuf[slot1] = (unsigned)sv.y | ((unsigned)(dv.y & 255) << 17);
  }
}

// ---------- parallel scan of bucket totals (1 block, 512 threads) ----------
__global__ void k_bucketscan(const int* __restrict__ gcursor, int* __restrict__ gbase,
                             int* __restrict__ offs) {
  __shared__ int ws[8];
  int t = threadIdx.x;
  int v = (t < NB) ? (gcursor[t] - t * CAP) : 0;
  int lane = t & 63, w = t >> 6;
  int inc = v;
#pragma unroll
  for (int off = 1; off < 64; off <<= 1) {
    int y = __shfl_up(inc, off, 64);
    if (lane >= off) inc += y;
  }
  if (lane == 63) ws[w] = inc;
  __syncthreads();
  int woff = 0;
  for (int i = 0; i < w; ++i) woff += ws[i];
  if (t < NB) gbase[t] = woff + inc - v;
  if (t == NB - 1) {
    gbase[NB] = woff + inc;
    offs[NN] = woff + inc;   // == NE
  }
}

// ---------- pass 2: LDS-staged per-bucket histogram/scan -> offs, dis, xs16, csr ----------
__global__ void k_csr(const unsigned* __restrict__ ebuf, const int* __restrict__ dirs,
                      const ushort* __restrict__ dirl, const int* __restrict__ gbase,
                      const int* __restrict__ gcur, const float* __restrict__ x,
                      int* __restrict__ offs, float* __restrict__ dis,
                      unsigned* __restrict__ xs16, int* __restrict__ csr, int n) {
  __shared__ unsigned sh[CAP];
  __shared__ int histc[256];
  __shared__ int loffs[256];
  __shared__ int wps[4];
  int t = threadIdx.x, j = blockIdx.x;
  int used = gcur[j] - j * CAP;
  for (int k = t; k < used; k += 256) sh[k] = ebuf[j * CAP + k];  // coalesced stage
  histc[t] = 0;
  __syncthreads();
  int rel = dirs[t * NB + j] - j * CAP;
  int clen = dirl[t * NB + j];
  for (int k = 0; k < clen; ++k) {
    atomicAdd(&histc[sh[rel + k] >> 17], 1);
  }
  __syncthreads();
  int h = histc[t];
  int inc = h;
  int lane = t & 63;
#pragma unroll
  for (int off = 1; off < 64; off <<= 1) {
    int y = __shfl_up(inc, off, 64);
    if (lane >= off) inc += y;
  }
  if (lane == 63) wps[t >> 6] = inc;
  __syncthreads();
  int woff = 0;
  for (int i = 0; i < (t >> 6); ++i) woff += wps[i];
  int excl = gbase[j] + woff + inc - h;
  loffs[t] = excl;
  int node = j * 256 + t;
  if (node < n) {
    offs[node] = excl;
    float dd = rsqrtf((float)(h + 1));
    dis[node] = dd;
    const float* xr = x + (size_t)node * 10;
#pragma unroll
    for (int q = 0; q < 8; ++q) {
      float a = (2 * q < 10) ? xr[2 * q] * dd : 0.f;
      float bb = (2 * q + 1 < 10) ? xr[2 * q + 1] * dd : 0.f;
      xs16[node * 8 + q] = bf_pack(a, bb);
    }
  }
  __syncthreads();
  for (int k = 0; k < clen; ++k) {
    unsigned u = sh[rel + k];
    int src = (int)(u & 0x1FFFFu);
    int slot = atomicAdd(&loffs[u >> 17], 1);
    csr[slot] = src;
  }
}

// ---------- layer 1: gather 16-wide (8-deep unroll) + batched dense 10x128 ----------

__global__ void k_gather16(const int* __restrict__ offs, const int* __restrict__ csr,
                           const float* __restrict__ dis, const unsigned* __restrict__ xs16,
                           float2* __restrict__ agg, int n) {
  int wid = (blockIdx.x * blockDim.x + threadIdx.x) >> 6;
  int lane = threadIdx.x & 63;
  int g = lane >> 3, sl = lane & 7;
  int node = wid * 8 + g;
  if (node >= n) return;
  unsigned self = xs16[node * 8 + sl];
  float sx = bf_lo(self), sy = bf_hi(self);
  float tx = 0.f, ty = 0.f;
  int e = offs[node], end = offs[node + 1];
  for (; e + 7 < end; e += 8) {
    int s0 = csr[e],     s1 = csr[e + 1], s2 = csr[e + 2], s3 = csr[e + 3];
    int s4 = csr[e + 4], s5 = csr[e + 5], s6 = csr[e + 6], s7 = csr[e + 7];
    unsigned u0 = xs16[s0 * 8 + sl], u1 = xs16[s1 * 8 + sl];
    unsigned u2 = xs16[s2 * 8 + sl], u3 = xs16[s3 * 8 + sl];
    unsigned u4 = xs16[s4 * 8 + sl], u5 = xs16[s5 * 8 + sl];
    unsigned u6 = xs16[s6 * 8 + sl], u7 = xs16[s7 * 8 + sl];
    sx += bf_lo(u0) + bf_lo(u1) + bf_lo(u2) + bf_lo(u3);
    sy += bf_hi(u0) + bf_hi(u1) + bf_hi(u2) + bf_hi(u3);
    tx += bf_lo(u4) + bf_lo(u5) + bf_lo(u6) + bf_lo(u7);
    ty += bf_hi(u4) + bf_hi(u5) + bf_hi(u6) + bf_hi(u7);
  }
  if (e + 3 < end) {
    int s0 = csr[e], s1 = csr[e + 1], s2 = csr[e + 2], s3 = csr[e + 3];
    unsigned u0 = xs16[s0 * 8 + sl], u1 = xs16[s1 * 8 + sl];
    unsigned u2 = xs16[s2 * 8 + sl], u3 = xs16[s3 * 8 + sl];
    sx += bf_lo(u0) + bf_lo(u1); tx += bf_lo(u2) + bf_lo(u3);
    sy += bf_hi(u0) + bf_hi(u1); ty += bf_hi(u2) + bf_hi(u3);
    e += 4;
  }
  for (; e < end; ++e) {
    unsigned v0 = xs16[csr[e] * 8 + sl];
    sx += bf_lo(v0); sy += bf_hi(v0);
  }
  float dd = dis[node];
  float2 o; o.x = (sx + tx) * dd; o.y = (sy + ty) * dd;
  agg[node * 8 + sl] = o;
}

// 16 nodes/block: agg staged in LDS, W1 column in registers
__global__ void k_mm16(const float* __restrict__ agg, const float* __restrict__ W1,
                       const float* __restrict__ b1, ushort* __restrict__ xbuf, int n) {
  __shared__ float as[16][16];
  int t = threadIdx.x;
  int n0 = blockIdx.x * 16;
  int lnode = t >> 4;
  int node = n0 + lnode;
  float v = (node < n) ? agg[(size_t)node * 16 + (t & 15)] : 0.f;
  as[lnode][t & 15] = v;
  __syncthreads();
  int m = t & 127;
  int half = t >> 7;   // 0 or 1 -> nodes 0-7 / 8-15
  float w0 = W1[0 * H + m], w1 = W1[1 * H + m], w2 = W1[2 * H + m];
  float w3 = W1[3 * H + m], w4 = W1[4 * H + m], w5 = W1[5 * H + m];
  float w6 = W1[6 * H + m], w7 = W1[7 * H + m], w8 = W1[8 * H + m];
  float w9 = W1[9 * H + m];
  float bm = b1[m];
#pragma unroll
  for (int j = 0; j < 8; ++j) {
    int nl = half * 8 + j;
    int nd = n0 + nl;
    if (nd < n) {
      float s = bm;
      s += as[nl][0] * w0 + as[nl][1] * w1 + as[nl][2] * w2 + as[nl][3] * w3;
      s += as[nl][4] * w4 + as[nl][5] * w5 + as[nl][6] * w6 + as[nl][7] * w7;
      s += as[nl][8] * w8 + as[nl][9] * w9;
      xbuf[(size_t)nd * H + m] = bf1(fmaxf(s, 0.f));
    }
  }
}

// ---------- layers 2/3 dense via MFMA: hs8 = fp8( (xb @ W) * dis ) ----------
__global__ void k_mm128_mfma(const short* __restrict__ xb,     // bf16 [n][128]
                             const short* __restrict__ Wfrag,  // [8][4][64][8]
                             const float* __restrict__ dis,
                             unsigned* __restrict__ hs8, int n) {
  int t = threadIdx.x;
  int lane = t & 63, w = t >> 6;
  int nbase = blockIdx.x * 64 + w * 16;
  int node = nbase + (lane & 15);
  bool valid = node < n;
  int nc = valid ? node : (n - 1);
  short8 xf0, xf1, xf2, xf3;
  const short* xrow = xb + (size_t)nc * H + (lane >> 4) * 8;
  xf0 = *(const short8*)(xrow);
  xf1 = *(const short8*)(xrow + 32);
  xf2 = *(const short8*)(xrow + 64);
  xf3 = *(const short8*)(xrow + 96);
  float d = dis[nc];
  const short8* wf = (const short8*)Wfrag;
#pragma unroll
  for (int nt = 0; nt < 8; ++nt) {
    f32x4 acc = {0.f, 0.f, 0.f, 0.f};
    acc = __builtin_amdgcn_mfma_f32_16x16x32_bf16(wf[(nt * 4 + 0) * 64 + lane], xf0, acc, 0, 0, 0);
    acc = __builtin_amdgcn_mfma_f32_16x16x32_bf16(wf[(nt * 4 + 1) * 64 + lane], xf1, acc, 0, 0, 0);
    acc = __builtin_amdgcn_mfma_f32_16x16x32_bf16(wf[(nt * 4 + 2) * 64 + lane], xf2, acc, 0, 0, 0);
    acc = __builtin_amdgcn_mfma_f32_16x16x32_bf16(wf[(nt * 4 + 3) * 64 + lane], xf3, acc, 0, 0, 0);
    if (valid) {
      int pk = __builtin_amdgcn_cvt_pk_fp8_f32(acc[0] * d, acc[1] * d, 0, false);
      pk = __builtin_amdgcn_cvt_pk_fp8_f32(acc[2] * d, acc[3] * d, pk, true);
      hs8[node * 32 + nt * 4 + (lane >> 4)] = (unsigned)pk;
    }
  }
}

// ---------- gather 128-wide: one node per wave, TWO edges per VMEM inst ----------
// Array-free (named scalars only) so nothing can be LDS/scratch-promoted.
#define RFL(v) __builtin_amdgcn_readfirstlane(v)
#define LOADP(sa, sb) hsu[(size_t)(hihalf ? (sb) : (sa)) * 32 + q]
#define ACCU(uu) { \
    v2f lo_ = __builtin_amdgcn_cvt_pk_f32_fp8((int)(uu), false); \
    v2f hi_ = __builtin_amdgcn_cvt_pk_f32_fp8((int)(uu), true);  \
    a0 += lo_.x; a1 += lo_.y; a2 += hi_.x; a3 += hi_.y; }

template <bool RELU, bool BIAS, bool OUTBF>
__global__ void k_gather(const int* __restrict__ offs, const int* __restrict__ csr,
                         const float* __restrict__ dis, const unsigned* __restrict__ hsu,
                         const float* __restrict__ b, void* __restrict__ outp, int n) {
  int node = (blockIdx.x * blockDim.x + threadIdx.x) >> 6;
  node = RFL(node);
  int lane = threadIdx.x & 63;
  int q = lane & 31;
  bool hihalf = lane >= 32;
  if (node >= n) return;
  float a0 = 0.f, a1 = 0.f, a2 = 0.f, a3 = 0.f;
  float mhi = hihalf ? 0.f : 1.f;   // mask for half-1-absent slots
  int e = RFL(offs[node]);
  int end = RFL(offs[node + 1]);

  // prologue pair: self (half 0) + first edge (half 1, masked if absent)
  {
    bool haveB = e < end;
    int sB = haveB ? RFL(csr[e]) : node;
    unsigned u = LOADP(node, sB);
    v2f lo = __builtin_amdgcn_cvt_pk_f32_fp8((int)u, false);
    v2f hi = __builtin_amdgcn_cvt_pk_f32_fp8((int)u, true);
    if (haveB) {
      a0 += lo.x; a1 += lo.y; a2 += hi.x; a3 += hi.y;
      ++e;
    } else {
      a0 += lo.x * mhi; a1 += lo.y * mhi; a2 += hi.x * mhi; a3 += hi.y * mhi;
    }
  }

  for (; e + 15 < end; e += 16) {   // 8 pairs, fully scalar-named
    int s0 = RFL(csr[e]),      s1 = RFL(csr[e + 1]);
    int s2 = RFL(csr[e + 2]),  s3 = RFL(csr[e + 3]);
    int s4 = RFL(csr[e + 4]),  s5 = RFL(csr[e + 5]);
    int s6 = RFL(csr[e + 6]),  s7 = RFL(csr[e + 7]);
    int s8 = RFL(csr[e + 8]),  s9 = RFL(csr[e + 9]);
    int sA = RFL(csr[e + 10]), sB = RFL(csr[e + 11]);
    int sC = RFL(csr[e + 12]), sD = RFL(csr[e + 13]);
    int sE = RFL(csr[e + 14]), sF = RFL(csr[e + 15]);
    unsigned u0 = LOADP(s0, s1);
    unsigned u1 = LOADP(s2, s3);
    unsigned u2 = LOADP(s4, s5);
    unsigned u3 = LOADP(s6, s7);
    unsigned u4 = LOADP(s8, s9);
    unsigned u5 = LOADP(sA, sB);
    unsigned u6 = LOADP(sC, sD);
    unsigned u7 = LOADP(sE, sF);
    ACCU(u0); ACCU(u1); ACCU(u2); ACCU(u3);
    ACCU(u4); ACCU(u5); ACCU(u6); ACCU(u7);
  }
  if (e + 7 < end) {                // 4 pairs
    int s0 = RFL(csr[e]),     s1 = RFL(csr[e + 1]);
    int s2 = RFL(csr[e + 2]), s3 = RFL(csr[e + 3]);
    int s4 = RFL(csr[e + 4]), s5 = RFL(csr[e + 5]);
    int s6 = RFL(csr[e + 6]), s7 = RFL(csr[e + 7]);
    unsigned u0 = LOADP(s0, s1);
    unsigned u1 = LOADP(s2, s3);
    unsigned u2 = LOADP(s4, s5);
    unsigned u3 = LOADP(s6, s7);
    ACCU(u0); ACCU(u1); ACCU(u2); ACCU(u3);
    e += 8;
  }
  if (e + 3 < end) {                // 2 pairs
    int s0 = RFL(csr[e]),     s1 = RFL(csr[e + 1]);
    int s2 = RFL(csr[e + 2]), s3 = RFL(csr[e + 3]);
    unsigned u0 = LOADP(s0, s1);
    unsigned u1 = LOADP(s2, s3);
    ACCU(u0); ACCU(u1);
    e += 4;
  }
  if (e + 1 < end) {                // 1 pair
    int s0 = RFL(csr[e]), s1 = RFL(csr[e + 1]);
    unsigned u0 = LOADP(s0, s1);
    ACCU(u0);
    e += 2;
  }
  if (e < end) {                    // final single edge (half 0 only, uniform row)
    int s0 = RFL(csr[e]);
    unsigned u = hsu[(size_t)s0 * 32 + q];
    v2f lo = __builtin_amdgcn_cvt_pk_f32_fp8((int)u, false);
    v2f hi = __builtin_amdgcn_cvt_pk_f32_fp8((int)u, true);
    a0 += lo.x * mhi; a1 += lo.y * mhi; a2 += hi.x * mhi; a3 += hi.y * mhi;
  }

  // merge halves via ds_bpermute lane^32 (no LDS allocation)
  a0 += swap32(a0);
  a1 += swap32(a1);
  a2 += swap32(a2);
  a3 += swap32(a3);

  if (!hihalf) {
    float dd = dis[node];
    float v0 = a0 * dd, v1 = a1 * dd, v2 = a2 * dd, v3 = a3 * dd;
    if (BIAS) {
      float4 bb = ((const float4*)b)[q];
      v0 += bb.x; v1 += bb.y; v2 += bb.z; v3 += bb.w;
    }
    if (RELU) {
      v0 = fmaxf(v0, 0.f); v1 = fmaxf(v1, 0.f);
      v2 = fmaxf(v2, 0.f); v3 = fmaxf(v3, 0.f);
    }
    if (OUTBF) {
      uint2 o;
      o.x = bf_pack(v0, v1);
      o.y = bf_pack(v2, v3);
      ((uint2*)outp)[(size_t)node * 32 + q] = o;
    } else {
      float4 o; o.x = v0; o.y = v1; o.z = v2; o.w = v3;
      ((float4*)outp)[(size_t)node * 32 + q] = o;
    }
  }
}

// ---------- pooling / output ----------

// acc is bf16 [n][128] read as u32 pairs; 64 threads/block, 2 feats/thread
__global__ void k_pool(const unsigned* __restrict__ acc, const float* __restrict__ b3,
                       const int* __restrict__ batch, float* pool, float* cnt, int n) {
  int m = threadIdx.x;          // 0..63 feature-pair index
  int n0 = blockIdx.x * 64;
  float rx = 0.f, ry = 0.f, crun = 0.f;
  int curg = -1;
  float2 bm = ((const float2*)b3)[m];
  for (int i = 0; i < 64; ++i) {
    int node = n0 + i;
    if (node >= n) break;
    int g = batch[node];
    if (g != curg) {
      if (curg >= 0) {
        atomicAdd(&pool[curg * H + 2 * m], rx);
        atomicAdd(&pool[curg * H + 2 * m + 1], ry);
        if (m == 0) atomicAdd(&cnt[curg], crun);
      }
      curg = g; rx = 0.f; ry = 0.f; crun = 0.f;
    }
    unsigned u = acc[(size_t)node * 64 + m];
    rx += bf_lo(u) + bm.x;
    ry += bf_hi(u) + bm.y;
    crun += 1.f;
  }
  if (curg >= 0) {
    atomicAdd(&pool[curg * H + 2 * m], rx);
    atomicAdd(&pool[curg * H + 2 * m + 1], ry);
    if (m == 0) atomicAdd(&cnt[curg], crun);
  }
}

__global__ void k_out(const float* __restrict__ pool, const float* __restrict__ cnt,
                      const float* __restrict__ Wlin, const float* __restrict__ blin,
                      float* __restrict__ out) {
  int t = threadIdx.x;
  if (t >= NG * 3) return;
  int g = t / 3, c = t % 3;
  float invc = 1.f / fmaxf(cnt[g], 1.f);
  float s = 0.f;
  for (int m = 0; m < H; ++m) s += pool[g * H + m] * Wlin[m * 3 + c];
  out[t] = s * invc + blin[c];
}

extern "C" void kernel_launch(void* const* d_in, const int* in_sizes, int n_in,
                              void* d_out, int out_size, void* d_ws, size_t ws_size,
                              hipStream_t stream) {
  const float* x     = (const float*)d_in[0];
  const int*   ei    = (const int*)d_in[1];
  const int*   batch = (const int*)d_in[2];
  const float* W1    = (const float*)d_in[3];
  const float* b1    = (const float*)d_in[4];
  const float* W2    = (const float*)d_in[5];
  const float* b2    = (const float*)d_in[6];
  const float* W3    = (const float*)d_in[7];
  const float* b3    = (const float*)d_in[8];
  const float* Wlin  = (const float*)d_in[9];
  const float* blin  = (const float*)d_in[10];
  float* out = (float*)d_out;

  char* ws = (char*)d_ws;
  float*    dis    = (float*)ws;     ws += sizeof(float) * NN;
  unsigned* hs8    = (unsigned*)ws;  ws += (size_t)NN * H;                  // fp8
  ushort*   xbuf   = (ushort*)ws;    ws += sizeof(ushort) * (size_t)NN * H; // bf16
  short*    WfragA = (short*)ws;     ws += sizeof(short) * 16384;
  short*    WfragB = (short*)ws;     ws += sizeof(short) * 16384;
  unsigned* xs16   = (unsigned*)ws;  ws += sizeof(unsigned) * (size_t)NN * 8;
  float*    agg    = (float*)ws;     ws += sizeof(float) * (size_t)NN * 16;
  float*    pool   = (float*)ws;     ws += sizeof(float) * NG * H;
  float*    cnt    = (float*)ws;     ws += sizeof(float) * NG;
  int*      offs   = (int*)ws;       ws += sizeof(int) * (NN + 8);
  int*      csr    = (int*)ws;       ws += sizeof(int) * NE;
  unsigned* ebuf   = (unsigned*)ws;  ws += sizeof(unsigned) * (size_t)NB * CAP;
  int*      dirs   = (int*)ws;       ws += sizeof(int) * P1B * NB;
  ushort*   dirl   = (ushort*)ws;    ws += sizeof(ushort) * P1B * NB;
  int*      gcur   = (int*)ws;       ws += sizeof(int) * NB;
  int*      gbase  = (int*)ws;       ws += sizeof(int) * (NB + 1);

  // init + W pack (fused), then CSR build: LDS-bucketed counting sort
  k_cvtinit<<<128, 256, 0, stream>>>(W2, W3, WfragA, WfragB, pool, cnt, gcur);
  k_bucket<<<P1B, 256, 0, stream>>>(ei, gcur, ebuf, dirs, dirl);
  k_bucketscan<<<1, 512, 0, stream>>>(gcur, gbase, offs);
  k_csr<<<NB, 256, 0, stream>>>(ebuf, dirs, dirl, gbase, gcur, x, offs, dis, xs16, csr, NN);

  const int GATHER_GRID = (NN + 3) / 4;   // 1 node/wave, 4 waves/block
  const int MM_GRID = (NN + 63) / 64;     // 64 nodes/block (16/wave)

  // layer 1: aggregate-first (A·X)·W1
  k_gather16<<<(NN + 31) / 32, 256, 0, stream>>>(offs, csr, dis, xs16, (float2*)agg, NN);
  k_mm16<<<(NN + 15) / 16, 256, 0, stream>>>(agg, W1, b1, xbuf, NN);

  // layer 2
  k_mm128_mfma<<<MM_GRID, 256, 0, stream>>>((const short*)xbuf, WfragA, dis, hs8, NN);
  k_gather<true, true, true><<<GATHER_GRID, 256, 0, stream>>>(
      offs, csr, dis, hs8, b2, xbuf, NN);

  // layer 3
  k_mm128_mfma<<<MM_GRID, 256, 0, stream>>>((const short*)xbuf, WfragB, dis, hs8, NN);
  k_gather<false, false, true><<<GATHER_GRID, 256, 0, stream>>>(
      offs, csr, dis, hs8, nullptr, xbuf, NN);

  // pool + head
  k_pool<<<(NN + 63) / 64, 64, 0, stream>>>((const unsigned*)xbuf, b3, batch, pool, cnt, NN);
  k_out<<<1, 256, 0, stream>>>(pool, cnt, Wlin, blin, out);
}